// Round 14
// baseline (322.538 us; speedup 1.0000x reference)
//
#include <hip/hip_runtime.h>

typedef unsigned short u16;
typedef unsigned int   u32;

#define LOG2E 1.44269504088896340736f

// ---------------- dims ----------------
#define BT_TOT   8192      // B*T
#define SEQ      4096
#define DMODEL   1024
#define DINNER   2048
#define NHEADS   32
#define HEADDIM  64
#define DSTATE   128
#define CONVDIM  2304
#define DINPROJ  4384
#define NCHUNK   32        // per batch
#define CHUNKQ   128

typedef float  f32x4  __attribute__((ext_vector_type(4)));
typedef __bf16 bf16x8 __attribute__((ext_vector_type(8)));

// XOR swizzle of a byte offset within a 256B (or 128B) row
#define SWB(r, b) ((b) ^ (((r) & 7) << 4))

__device__ __forceinline__ u16 f2bf(float f) {
  u32 u = __float_as_uint(f);
  u += 0x7fffu + ((u >> 16) & 1u);
  return (u16)(u >> 16);
}
__device__ __forceinline__ float bf2f(u16 s) {
  return __uint_as_float(((u32)s) << 16);
}

// async global->LDS, 16B per lane; lds dest must be wave-uniform base (+lane*16 implicit)
__device__ __forceinline__ void async_cp16(const void* g, void* l) {
  __builtin_amdgcn_global_load_lds((const __attribute__((address_space(1))) u32*)g,
                                   (__attribute__((address_space(3))) u32*)l, 16, 0, 0);
}

union bfpack { u16 u[8]; bf16x8 v; };

// ---------------- cast f32 -> bf16 (8 elems/thread) ----------------
__global__ __launch_bounds__(256) void cast_bf16(const float* __restrict__ in,
                                                 u16* __restrict__ out, int n8) {
  int i = blockIdx.x * 256 + threadIdx.x;
  if (i >= n8) return;
  const float4* p = (const float4*)in + (size_t)i * 2;
  float4 a = p[0], b = p[1];
  uint4 o;
  o.x = (u32)f2bf(a.x) | ((u32)f2bf(a.y) << 16);
  o.y = (u32)f2bf(a.z) | ((u32)f2bf(a.w) << 16);
  o.z = (u32)f2bf(b.x) | ((u32)f2bf(b.y) << 16);
  o.w = (u32)f2bf(b.z) | ((u32)f2bf(b.w) << 16);
  ((uint4*)out)[i] = o;
}

// ---------------- transpose + cast: in (R,C) f32 -> out (C,R) bf16 ----------------
__global__ __launch_bounds__(256) void tcast(const float* __restrict__ in,
                                             u16* __restrict__ out, int R, int C) {
  __shared__ float tile[32][33];
  int c0 = blockIdx.x * 32, r0 = blockIdx.y * 32;
  int tx = threadIdx.x & 31, ty = threadIdx.x >> 5;  // ty 0..7
  for (int dy = 0; dy < 32; dy += 8)
    tile[ty + dy][tx] = in[(size_t)(r0 + ty + dy) * C + c0 + tx];
  __syncthreads();
  for (int dy = 0; dy < 32; dy += 8)
    out[(size_t)(c0 + ty + dy) * R + r0 + tx] = f2bf(tile[tx][ty + dy]);
}

// ================= GEMM cores (r12 proven: 128x128, BK=64, 2-phase dbuf, 64KB LDS,
//   XCD-chunked + L2-panel ordering). gemm_in is PERSISTENT: 512 blocks, each
//   processes tiles pb, pb+512, ... -> no ragged 5th scheduling round (was 4.375
//   rounds of 512-resident blocks; tail wasted ~13us). 512%8==0 keeps XCD affinity.

// ---- GEMM1: zxbcdt = xb @ Win^T with split epilogue ----
__global__ __launch_bounds__(256) void gemm_in(const u16* __restrict__ A,
                                               const u16* __restrict__ Bt,
                                               const float* __restrict__ dt_bias,
                                               u16* __restrict__ zb,
                                               u16* __restrict__ xbcb,
                                               float* __restrict__ dtb) {
  const int K = DMODEL, Nn = DINPROJ;
  __shared__ u16 sh[32768];
  const int tid = threadIdx.x, lane = tid & 63, wave = tid >> 6;
  const int wm = (wave >> 1) << 6, wn = (wave & 1) << 6;
  const int pb = blockIdx.x;          // 0..511

  for (int tile = pb; tile < 2240; tile += 512) {
    int xcd = tile & 7, c = tile >> 3;          // c in [0,280)
    int dm, n;
    if (c < 256) { int p = c >> 6, r = c & 63; n = p * 8 + (r & 7); dm = r >> 3; }
    else         { int r = c - 256;            n = 32 + r % 3;      dm = r / 3;  }
    const int m0 = (xcd * 8 + dm) * 128;
    const int n0 = n * 128;

    f32x4 acc[4][4] = {};

    auto issue = [&](int buf, int k0) {
#pragma unroll
      for (int s = 0; s < 4; ++s) {
        int idx = s * 256 + tid;
        int row = idx >> 3, k16 = idx & 7;
        int swo = (k16 * 8) ^ ((row & 7) << 3);          // u16 units
        int lofs = (s * 256 + wave * 64) * 8;            // wave-uniform u16 offset
        async_cp16(A + (size_t)(m0 + row) * K + k0 + swo, sh + buf * 16384 + lofs);
        int rn = n0 + row; if (rn > Nn - 1) rn = Nn - 1;
        async_cp16(Bt + (size_t)rn * K + k0 + swo, sh + buf * 16384 + 8192 + lofs);
      }
    };
    issue(0, 0);
    const int nk = K / 64;
    for (int kt = 0; kt < nk; ++kt) {
      int buf = kt & 1;
      asm volatile("s_waitcnt vmcnt(0)" ::: "memory");
      __syncthreads();
      if (kt + 1 < nk) issue(buf ^ 1, (kt + 1) * 64);
      const char* As = (const char*)(sh + buf * 16384);
      const char* Bs = (const char*)(sh + buf * 16384 + 8192);
#pragma unroll
      for (int ks = 0; ks < 2; ++ks) {
        bf16x8 af[4], bfr[4];
#pragma unroll
        for (int t = 0; t < 4; ++t) {
          int r  = wm + t * 16 + (lane & 15);
          int kb = ks * 64 + ((lane >> 4) << 4);
          af[t]  = *(const bf16x8*)(As + r * 128 + SWB(r, kb));
          int rn = wn + t * 16 + (lane & 15);
          bfr[t] = *(const bf16x8*)(Bs + rn * 128 + SWB(rn, kb));
        }
#pragma unroll
        for (int mi = 0; mi < 4; ++mi)
#pragma unroll
          for (int ni = 0; ni < 4; ++ni)
            acc[mi][ni] = __builtin_amdgcn_mfma_f32_16x16x32_bf16(af[mi], bfr[ni], acc[mi][ni], 0, 0, 0);
      }
    }
    __syncthreads();
    if (n0 == 4352) {  // dt block: scalar softplus epilogue (only 32 valid cols)
#pragma unroll
      for (int mi = 0; mi < 4; ++mi) {
#pragma unroll
        for (int ni = 0; ni < 4; ++ni) {
          int r0 = m0 + wm + mi * 16 + ((lane >> 4) << 2);
          int c2 = n0 + wn + ni * 16 + (lane & 15);
          if (c2 < DINPROJ) {
            int h = c2 - 4352;
            float bias = dt_bias[h];
#pragma unroll
            for (int j = 0; j < 4; ++j) {
              float v = acc[mi][ni][j] + bias;
              dtb[(size_t)(r0 + j) * NHEADS + h] = (v > 20.f) ? v : log1pf(__expf(v));
            }
          }
        }
      }
    } else {
      // stage bf16 tile into LDS, then coalesced uint4 writes
#pragma unroll
      for (int mi = 0; mi < 4; ++mi)
#pragma unroll
        for (int ni = 0; ni < 4; ++ni) {
          int il = wm + mi * 16 + ((lane >> 4) << 2);
          int cl = wn + ni * 16 + (lane & 15);
#pragma unroll
          for (int j = 0; j < 4; ++j)
            *(u16*)((char*)sh + (il + j) * 256 + SWB(il + j, 2 * cl)) = f2bf(acc[mi][ni][j]);
        }
      __syncthreads();
      u16* dst; int ldst, n0c;
      if (n0 < 2048) { dst = zb;   ldst = DINNER;  n0c = n0; }
      else           { dst = xbcb; ldst = CONVDIM; n0c = n0 - 2048; }
#pragma unroll
      for (int s = 0; s < 8; ++s) {   // 128 rows x 16 uint4 = 2048 = 8*256
        int idx = s * 256 + tid;
        int r = idx >> 4, n16 = idx & 15;
        uint4 v = *(const uint4*)((char*)sh + r * 256 + SWB(r, n16 * 16));
        *(uint4*)(dst + (size_t)(m0 + r) * ldst + n0c + n16 * 8) = v;
      }
    }
    __syncthreads();   // staging LDS reads done before next tile's issue(0) overwrites
  }
}

// ---- GEMM2: out = yb @ Wout^T, f32 output (512 blocks = exactly 2/CU, no tail) ----
__global__ __launch_bounds__(256) void gemm_out(const u16* __restrict__ A,
                                                const u16* __restrict__ Bt,
                                                float* __restrict__ C) {
  const int K = DINNER, Nn = DMODEL;
  __shared__ u16 sh[32768];
  const int tid = threadIdx.x, lane = tid & 63, wave = tid >> 6;
  const int wm = (wave >> 1) << 6, wn = (wave & 1) << 6;
  // grid (8,64) -> 512 blocks, 64/XCD; panels of 4n x 8m (WS = 2MB+2MB)
  int flat = blockIdx.y * gridDim.x + blockIdx.x;
  int xcd = flat & 7, c = flat >> 3;          // c in [0,64)
  int p = c >> 5, r = c & 31;
  int n = p * 4 + (r & 3), dm = r >> 2;
  const int m0 = (xcd * 8 + dm) * 128;
  const int n0 = n * 128;

  f32x4 acc[4][4] = {};
  auto issue = [&](int buf, int k0) {
#pragma unroll
    for (int s = 0; s < 4; ++s) {
      int idx = s * 256 + tid;
      int row = idx >> 3, k16 = idx & 7;
      int swo = (k16 * 8) ^ ((row & 7) << 3);
      int lofs = (s * 256 + wave * 64) * 8;
      async_cp16(A + (size_t)(m0 + row) * K + k0 + swo, sh + buf * 16384 + lofs);
      async_cp16(Bt + (size_t)(n0 + row) * K + k0 + swo, sh + buf * 16384 + 8192 + lofs);
    }
  };
  issue(0, 0);
  const int nk = K / 64;
  for (int kt = 0; kt < nk; ++kt) {
    int buf = kt & 1;
    asm volatile("s_waitcnt vmcnt(0)" ::: "memory");
    __syncthreads();
    if (kt + 1 < nk) issue(buf ^ 1, (kt + 1) * 64);
    const char* As = (const char*)(sh + buf * 16384);
    const char* Bs = (const char*)(sh + buf * 16384 + 8192);
#pragma unroll
    for (int ks = 0; ks < 2; ++ks) {
      bf16x8 af[4], bfr[4];
#pragma unroll
      for (int t = 0; t < 4; ++t) {
        int r2 = wm + t * 16 + (lane & 15);
        int kb = ks * 64 + ((lane >> 4) << 4);
        af[t]  = *(const bf16x8*)(As + r2 * 128 + SWB(r2, kb));
        int rn = wn + t * 16 + (lane & 15);
        bfr[t] = *(const bf16x8*)(Bs + rn * 128 + SWB(rn, kb));
      }
#pragma unroll
      for (int mi = 0; mi < 4; ++mi)
#pragma unroll
        for (int ni = 0; ni < 4; ++ni)
          acc[mi][ni] = __builtin_amdgcn_mfma_f32_16x16x32_bf16(af[mi], bfr[ni], acc[mi][ni], 0, 0, 0);
    }
  }
#pragma unroll
  for (int mi = 0; mi < 4; ++mi) {
#pragma unroll
    for (int ni = 0; ni < 4; ++ni) {
      int r0 = m0 + wm + mi * 16 + ((lane >> 4) << 2);
      int c2 = n0 + wn + ni * 16 + (lane & 15);
#pragma unroll
      for (int j = 0; j < 4; ++j)
        C[(size_t)(r0 + j) * Nn + c2] = acc[mi][ni][j];
    }
  }
}

// -------- depthwise causal conv1d + bias + silu: 8 ch x 8 timesteps per thread --------
// weights contiguous 128B/thread amortized over 8 outputs; tap rows in regs (11 uint4,
// read amplification 1.375x).
__global__ __launch_bounds__(256) void conv_silu(const u16* __restrict__ xbcb,
                                                 const float* __restrict__ cw,
                                                 const float* __restrict__ cb,
                                                 u16* __restrict__ convb) {
  int i = blockIdx.x * 256 + threadIdx.x;   // (BT_TOT/8) * 288 threads
  int bt8 = i / 288, c8 = i - bt8 * 288;
  int c0 = c8 * 8;
  int bt = bt8 * 8;                          // base output row (8 outputs)
  int t = bt & (SEQ - 1);

  float4 w[8];
  const float4* wp = (const float4*)(cw + (size_t)c0 * 4);
#pragma unroll
  for (int q = 0; q < 8; ++q) w[q] = wp[q];
  float4 b0 = ((const float4*)(cb + c0))[0];
  float4 b1 = ((const float4*)(cb + c0))[1];
  float bias[8] = {b0.x, b0.y, b0.z, b0.w, b1.x, b1.y, b1.z, b1.w};

  uint4 rows[11];
#pragma unroll
  for (int rix = 0; rix < 11; ++rix) {
    if (t - 3 + rix >= 0)
      rows[rix] = *(const uint4*)(xbcb + (size_t)(bt - 3 + rix) * CONVDIM + c0);
    else
      rows[rix] = make_uint4(0, 0, 0, 0);
  }

#pragma unroll
  for (int j = 0; j < 8; ++j) {
    float acc[8];
#pragma unroll
    for (int e = 0; e < 8; ++e) acc[e] = bias[e];
#pragma unroll
    for (int k = 0; k < 4; ++k) {
      const u16* e16 = (const u16*)&rows[j + k];
      float wk;
#pragma unroll
      for (int e = 0; e < 8; ++e) {
        wk = (k == 0) ? w[e].x : (k == 1) ? w[e].y : (k == 2) ? w[e].z : w[e].w;
        acc[e] = fmaf(bf2f(e16[e]), wk, acc[e]);
      }
    }
    uint4 o;
    u16* o16 = (u16*)&o;
#pragma unroll
    for (int e = 0; e < 8; ++e) {
      float s = acc[e] / (1.f + __expf(-acc[e]));
      o16[e] = f2bf(s);
    }
    *(uint4*)(convb + (size_t)(bt + j) * CONVDIM + c0) = o;
  }
}

// ---------------- per-(b,c,h) cumsum of dA over chunk; stores LOG2-domain ----------------
__global__ __launch_bounds__(128) void ssd_cumsum(const float* __restrict__ dtb,
                                                  const float* __restrict__ A_log,
                                                  float* __restrict__ dacs) {
  int bch = blockIdx.x;          // (b*32+c)*32+h
  int h = bch & 31, bc = bch >> 5;
  int q = threadIdx.x;
  float A = -__expf(A_log[h]);
  float v = dtb[((size_t)bc * 128 + q) * 32 + h] * A;
#pragma unroll
  for (int o = 1; o < 64; o <<= 1) {
    float u = __shfl_up(v, o, 64);
    if ((q & 63) >= o) v += u;
  }
  __shared__ float w0;
  if (q == 63) w0 = v;
  __syncthreads();
  if (q >= 64) v += w0;
  dacs[(size_t)bch * 128 + q] = v * LOG2E;
}

// ---------------- fused SSD intra per (b,c,h): G -> M -> Y_diag (+D*xh), S^T ----------------
__global__ __launch_bounds__(256) void ssd_intra2(const u16* __restrict__ convb,
                                                  const float* __restrict__ dacs,
                                                  const float* __restrict__ dtb,
                                                  const float* __restrict__ Dv,
                                                  u16* __restrict__ y,
                                                  u16* __restrict__ S) {
  __shared__ u16 Cc[128 * 128];
  __shared__ u16 Bb[128 * 128];
  __shared__ u16 xhT[64 * 128];
  int bch = (blockIdx.x & 7) * 256 + (blockIdx.x >> 3);  // XCD swizzle (2048 %8==0)
  int h = bch & 31, bc = bch >> 5;
  size_t row0 = (size_t)bc * 128;
  int tid = threadIdx.x, lane = tid & 63, wave = tid >> 6;
  const float* cs = dacs + (size_t)bch * 128;   // log2-domain cumsum

#pragma unroll
  for (int s = 0; s < 8; ++s) {
    int idx = s * 256 + tid;
    int r = idx >> 4, n16 = idx & 15;
    uint4 v = *(const uint4*)(convb + (row0 + r) * CONVDIM + (DINNER + DSTATE) + n16 * 8);
    *(uint4*)((char*)Cc + r * 256 + SWB(r, n16 * 16)) = v;
    uint4 w = *(const uint4*)(convb + (row0 + r) * CONVDIM + DINNER + n16 * 8);
    *(uint4*)((char*)Bb + r * 256 + SWB(r, n16 * 16)) = w;
  }
#pragma unroll
  for (int s = 0; s < 4; ++s) {
    int idx = s * 256 + tid;
    int q = idx >> 3, p0 = (idx & 7) * 8;
    uint4 v = *(const uint4*)(convb + (row0 + q) * CONVDIM + h * 64 + p0);
    const u16* e = (const u16*)&v;
#pragma unroll
    for (int k = 0; k < 8; ++k)
      *(u16*)((char*)xhT + (p0 + k) * 256 + SWB(p0 + k, 2 * q)) = e[k];
  }
  __syncthreads();

  // ---- G = C . B^T ----
  f32x4 g[2][8] = {};
#pragma unroll
  for (int ks = 0; ks < 4; ++ks) {
    int kb = ks * 64 + ((lane >> 4) << 4);
    bf16x8 a[2], b[8];
#pragma unroll
    for (int fi = 0; fi < 2; ++fi) {
      int r = 32 * wave + fi * 16 + (lane & 15);
      a[fi] = *(const bf16x8*)((const char*)Cc + r * 256 + SWB(r, kb));
    }
#pragma unroll
    for (int fj = 0; fj < 8; ++fj) {
      int rj = fj * 16 + (lane & 15);
      b[fj] = *(const bf16x8*)((const char*)Bb + rj * 256 + SWB(rj, kb));
    }
#pragma unroll
    for (int fi = 0; fi < 2; ++fi)
#pragma unroll
      for (int fj = 0; fj < 8; ++fj)
        g[fi][fj] = __builtin_amdgcn_mfma_f32_16x16x32_bf16(a[fi], b[fj], g[fi][fj], 0, 0, 0);
  }

  // ---- build M (bf16) into Cc rows owned by this wave ----
#pragma unroll
  for (int fi = 0; fi < 2; ++fi) {
    int ib = 32 * wave + fi * 16 + ((lane >> 4) << 2);
    float ci[4];
#pragma unroll
    for (int r = 0; r < 4; ++r) ci[r] = cs[ib + r];
#pragma unroll
    for (int fj = 0; fj < 8; ++fj) {
      int j = fj * 16 + (lane & 15);
      float cj = cs[j];
      float dj = dtb[(row0 + j) * NHEADS + h];
#pragma unroll
      for (int r = 0; r < 4; ++r) {
        int i = ib + r;
        float m = (j <= i) ? g[fi][fj][r] * exp2f(ci[r] - cj) * dj : 0.f;
        *(u16*)((char*)Cc + i * 256 + SWB(i, 2 * j)) = f2bf(m);
      }
    }
  }

  // ---- Y_diag = M . xh, triangular k-skip; + D*xh; store y (bf16) ----
  f32x4 yd[2][4] = {};
  for (int ks = 0; ks <= wave; ++ks) {
    int kb = ks * 64 + ((lane >> 4) << 4);
    bf16x8 a[2], b[4];
#pragma unroll
    for (int fi = 0; fi < 2; ++fi) {
      int r = 32 * wave + fi * 16 + (lane & 15);
      a[fi] = *(const bf16x8*)((const char*)Cc + r * 256 + SWB(r, kb));
    }
#pragma unroll
    for (int fp = 0; fp < 4; ++fp) {
      int pr = fp * 16 + (lane & 15);
      b[fp] = *(const bf16x8*)((const char*)xhT + pr * 256 + SWB(pr, kb));
    }
#pragma unroll
    for (int fi = 0; fi < 2; ++fi)
#pragma unroll
      for (int fp = 0; fp < 4; ++fp)
        yd[fi][fp] = __builtin_amdgcn_mfma_f32_16x16x32_bf16(a[fi], b[fp], yd[fi][fp], 0, 0, 0);
  }
  {
    float Dh = Dv[h];
#pragma unroll
    for (int fi = 0; fi < 2; ++fi) {
      int ib = 32 * wave + fi * 16 + ((lane >> 4) << 2);
#pragma unroll
      for (int fp = 0; fp < 4; ++fp) {
        int p = fp * 16 + (lane & 15);
#pragma unroll
        for (int r = 0; r < 4; ++r) {
          int i = ib + r;
          float xv = bf2f(*(const u16*)((const char*)xhT + p * 256 + SWB(p, 2 * i)));
          y[(row0 + i) * DINNER + h * 64 + p] = f2bf(yd[fi][fp][r] + Dh * xv);
        }
      }
    }
  }

  // ---- S[n][p] = sum_q (B[q][n]*w_q) * xh[q][p] ----
  float cl = cs[127];
  f32x4 sa[2][4] = {};
#pragma unroll
  for (int ks = 0; ks < 4; ++ks) {
    int qb = ks * 32 + ((lane >> 4) << 3);
    float wv[8];
#pragma unroll
    for (int e = 0; e < 8; ++e)
      wv[e] = exp2f(cl - cs[qb + e]) * dtb[(row0 + qb + e) * NHEADS + h];
    bf16x8 a[2], b[4];
#pragma unroll
    for (int fn = 0; fn < 2; ++fn) {
      int n = 32 * wave + fn * 16 + (lane & 15);
      bfpack t;
#pragma unroll
      for (int e = 0; e < 8; ++e) {
        int q = qb + e;
        float bv = bf2f(*(const u16*)((const char*)Bb + q * 256 + SWB(q, 2 * n)));
        t.u[e] = f2bf(bv * wv[e]);
      }
      a[fn] = t.v;
    }
    int kb = ks * 64 + ((lane >> 4) << 4);
#pragma unroll
    for (int fp = 0; fp < 4; ++fp) {
      int pr = fp * 16 + (lane & 15);
      b[fp] = *(const bf16x8*)((const char*)xhT + pr * 256 + SWB(pr, kb));
    }
#pragma unroll
    for (int fn = 0; fn < 2; ++fn)
#pragma unroll
      for (int fp = 0; fp < 4; ++fp)
        sa[fn][fp] = __builtin_amdgcn_mfma_f32_16x16x32_bf16(a[fn], b[fp], sa[fn][fp], 0, 0, 0);
  }
  __syncthreads();
#pragma unroll
  for (int fn = 0; fn < 2; ++fn) {
    int nb = 32 * wave + fn * 16 + ((lane >> 4) << 2);
#pragma unroll
    for (int fp = 0; fp < 4; ++fp) {
      int p = fp * 16 + (lane & 15);
#pragma unroll
      for (int r = 0; r < 4; ++r)
        *(u16*)((char*)Cc + p * 256 + SWB(p, 2 * (nb + r))) = f2bf(sa[fn][fp][r]);
    }
  }
  __syncthreads();
#pragma unroll
  for (int s = 0; s < 4; ++s) {
    int idx = s * 256 + tid;
    int p = idx >> 4, n16 = idx & 15;
    uint4 v = *(const uint4*)((char*)Cc + p * 256 + SWB(p, n16 * 16));
    *(uint4*)(S + (size_t)bch * 8192 + p * 128 + n16 * 8) = v;
  }
}

// ---------------- inter-chunk scan (in place; S layout [p][n] flat 8192/bch) -------
__global__ __launch_bounds__(256) void ssd_scan(u16* __restrict__ S,
                                                const float* __restrict__ dacs) {
  int f = blockIdx.x * 256 + threadIdx.x;   // 524288 total
  int e = f & 8191;
  int bh = f >> 13;
  int b = bh >> 5, h = bh & 31;
  float carry = 0.f;
  for (int c = 0; c < NCHUNK; ++c) {
    size_t bch = ((size_t)b * 32 + c) * 32 + h;
    size_t off = bch * 8192 + e;
    float s = bf2f(S[off]);
    S[off] = f2bf(carry);
    float cd = exp2f(dacs[bch * 128 + 127]);
    carry = fmaf(carry, cd, s);
  }
}

// ---------------- Y_off: y += exp2(cs_i) * C(128x128) . prev^T-layout (MFMA) ----------------
__global__ __launch_bounds__(256) void ssd_off2(const u16* __restrict__ convb,
                                                const u16* __restrict__ S,
                                                const float* __restrict__ dacs,
                                                u16* __restrict__ y) {
  __shared__ u16 Cc[128 * 128];
  __shared__ u16 pv[64 * 128];   // prev as [p][n]
  int bch = (blockIdx.x & 7) * 256 + (blockIdx.x >> 3);
  int h = bch & 31, bc = bch >> 5;
  size_t row0 = (size_t)bc * 128;
  int tid = threadIdx.x, lane = tid & 63, wave = tid >> 6;
  const float* cs = dacs + (size_t)bch * 128;

#pragma unroll
  for (int s = 0; s < 8; ++s) {
    int idx = s * 256 + tid;
    int r = idx >> 4, n16 = idx & 15;
    uint4 v = *(const uint4*)(convb + (row0 + r) * CONVDIM + (DINNER + DSTATE) + n16 * 8);
    *(uint4*)((char*)Cc + r * 256 + SWB(r, n16 * 16)) = v;
  }
#pragma unroll
  for (int s = 0; s < 4; ++s) {
    int idx = s * 256 + tid;
    int p = idx >> 4, n16 = idx & 15;
    uint4 v = *(const uint4*)(S + (size_t)bch * 8192 + p * 128 + n16 * 8);
    *(uint4*)((char*)pv + p * 256 + SWB(p, n16 * 16)) = v;
  }
  __syncthreads();

  f32x4 acc[2][4] = {};
#pragma unroll
  for (int ks = 0; ks < 4; ++ks) {
    int kb = ks * 64 + ((lane >> 4) << 4);
    bf16x8 a[2], b[4];
#pragma unroll
    for (int fi = 0; fi < 2; ++fi) {
      int r = 32 * wave + fi * 16 + (lane & 15);
      a[fi] = *(const bf16x8*)((const char*)Cc + r * 256 + SWB(r, kb));
    }
#pragma unroll
    for (int fp = 0; fp < 4; ++fp) {
      int pr = fp * 16 + (lane & 15);
      b[fp] = *(const bf16x8*)((const char*)pv + pr * 256 + SWB(pr, kb));
    }
#pragma unroll
    for (int fi = 0; fi < 2; ++fi)
#pragma unroll
      for (int fp = 0; fp < 4; ++fp)
        acc[fi][fp] = __builtin_amdgcn_mfma_f32_16x16x32_bf16(a[fi], b[fp], acc[fi][fp], 0, 0, 0);
  }
#pragma unroll
  for (int fi = 0; fi < 2; ++fi) {
    int ib = 32 * wave + fi * 16 + ((lane >> 4) << 2);
    float ei[4];
#pragma unroll
    for (int r = 0; r < 4; ++r) ei[r] = exp2f(cs[ib + r]);
#pragma unroll
    for (int fp = 0; fp < 4; ++fp) {
      int p = fp * 16 + (lane & 15);
#pragma unroll
      for (int r = 0; r < 4; ++r) {
        u16* yp = &y[(row0 + ib + r) * DINNER + h * 64 + p];
        float cur = bf2f(*yp);
        *yp = f2bf(fmaf(ei[r], acc[fi][fp][r], cur));
      }
    }
  }
}

// ---------------- gated RMSNorm -> bf16 ----------------
__global__ __launch_bounds__(256) void gated_norm(const u16* __restrict__ y,
                                                  const u16* __restrict__ zb,
                                                  const float* __restrict__ normw,
                                                  u16* __restrict__ yb) {
  size_t bt = blockIdx.x;
  int tid = threadIdx.x;
  const u16* yr = y + bt * DINNER;
  const u16* zr = zb + bt * DINNER;
  float g[8];
  float ss = 0.f;
#pragma unroll
  for (int s = 0; s < 8; ++s) {
    int c = tid + s * 256;
    float z = bf2f(zr[c]);
    float v = bf2f(yr[c]) * (z / (1.f + __expf(-z)));
    g[s] = v;
    ss = fmaf(v, v, ss);
  }
#pragma unroll
  for (int o = 1; o < 64; o <<= 1) ss += __shfl_xor(ss, o, 64);
  __shared__ float red[4];
  if ((tid & 63) == 0) red[tid >> 6] = ss;
  __syncthreads();
  float tot = red[0] + red[1] + red[2] + red[3];
  float r = rsqrtf(tot * (1.f / (float)DINNER) + 1e-5f);
#pragma unroll
  for (int s = 0; s < 8; ++s) {
    int c = tid + s * 256;
    yb[bt * DINNER + c] = f2bf(g[s] * r * normw[c]);
  }
}

// ---------------- workspace layout (~198 MiB) ----------------
constexpr size_t SZ_XB   = (size_t)BT_TOT * DMODEL * 2;
constexpr size_t SZ_WIB  = (size_t)DINPROJ * DMODEL * 2;
constexpr size_t SZ_WOB  = (size_t)DMODEL * DINNER * 2;
constexpr size_t SZ_ZB   = (size_t)BT_TOT * DINNER * 2;
constexpr size_t SZ_XBCB = (size_t)BT_TOT * CONVDIM * 2;   // reused by yb
constexpr size_t SZ_DTB  = (size_t)BT_TOT * NHEADS * 4;
constexpr size_t SZ_DACS = (size_t)2048 * 128 * 4;
constexpr size_t SZ_CONV = (size_t)BT_TOT * CONVDIM * 2;
constexpr size_t SZ_SB   = (size_t)2048 * 128 * 64 * 2;
constexpr size_t SZ_Y    = (size_t)BT_TOT * DINNER * 2;    // bf16

constexpr size_t OFF_XB   = 0;
constexpr size_t OFF_WIB  = OFF_XB + SZ_XB;
constexpr size_t OFF_WOB  = OFF_WIB + SZ_WIB;
constexpr size_t OFF_ZB   = OFF_WOB + SZ_WOB;
constexpr size_t OFF_XBCB = OFF_ZB + SZ_ZB;
constexpr size_t OFF_DTB  = OFF_XBCB + SZ_XBCB;
constexpr size_t OFF_DACS = OFF_DTB + SZ_DTB;
constexpr size_t OFF_CONV = OFF_DACS + SZ_DACS;
constexpr size_t OFF_SB   = OFF_CONV + SZ_CONV;
constexpr size_t OFF_Y    = OFF_SB + SZ_SB;
constexpr size_t WS_NEEDED = OFF_Y + SZ_Y;

extern "C" void kernel_launch(void* const* d_in, const int* in_sizes, int n_in,
                              void* d_out, int out_size, void* d_ws, size_t ws_size,
                              hipStream_t stream) {
  (void)in_sizes; (void)n_in; (void)out_size;
  if (ws_size < WS_NEEDED) return;

  const float* x      = (const float*)d_in[0];
  const float* Win    = (const float*)d_in[1];
  const float* cw     = (const float*)d_in[2];
  const float* cb     = (const float*)d_in[3];
  const float* dtbias = (const float*)d_in[4];
  const float* A_log  = (const float*)d_in[5];
  const float* Dv     = (const float*)d_in[6];
  const float* normw  = (const float*)d_in[7];
  const float* Wout   = (const float*)d_in[8];
  float* out = (float*)d_out;

  char* ws = (char*)d_ws;
  u16*   xb    = (u16*)  (ws + OFF_XB);
  u16*   wib   = (u16*)  (ws + OFF_WIB);
  u16*   wob   = (u16*)  (ws + OFF_WOB);
  u16*   zb    = (u16*)  (ws + OFF_ZB);
  u16*   xbcb  = (u16*)  (ws + OFF_XBCB);
  float* dtb   = (float*)(ws + OFF_DTB);
  float* dacs  = (float*)(ws + OFF_DACS);
  u16*   convb = (u16*)  (ws + OFF_CONV);
  u16*   sb    = (u16*)  (ws + OFF_SB);
  u16*   y     = (u16*)  (ws + OFF_Y);
  u16*   yb    = (u16*)  (ws + OFF_XBCB);  // overlay: xbcb dead after conv_silu

  cast_bf16<<<dim3(4096), dim3(256), 0, stream>>>(x, xb, BT_TOT * DMODEL / 8);
  tcast<<<dim3(DINPROJ / 32, DMODEL / 32), dim3(256), 0, stream>>>(Win, wib, DMODEL, DINPROJ);
  tcast<<<dim3(DMODEL / 32, DINNER / 32), dim3(256), 0, stream>>>(Wout, wob, DINNER, DMODEL);

  gemm_in<<<dim3(512), dim3(256), 0, stream>>>(xb, wib, dtbias, zb, xbcb, dtb);

  conv_silu<<<dim3((BT_TOT / 8) * (CONVDIM / 8) / 256), dim3(256), 0, stream>>>(
      xbcb, cw, cb, convb);
  ssd_cumsum<<<dim3(2048), dim3(128), 0, stream>>>(dtb, A_log, dacs);
  ssd_intra2<<<dim3(2048), dim3(256), 0, stream>>>(convb, dacs, dtb, Dv, y, sb);
  ssd_scan<<<dim3(2048), dim3(256), 0, stream>>>(sb, dacs);
  ssd_off2<<<dim3(2048), dim3(256), 0, stream>>>(convb, sb, dacs, y);
  gated_norm<<<dim3(BT_TOT), dim3(256), 0, stream>>>(y, zb, normw, yb);

  gemm_out<<<dim3(8, 64), dim3(256), 0, stream>>>(yb, wob, out);
}

// Round 15
// 320.866 us; speedup vs baseline: 1.0052x; 1.0052x over previous
//
#include <hip/hip_runtime.h>

typedef unsigned short u16;
typedef unsigned int   u32;

#define LOG2E 1.44269504088896340736f

// ---------------- dims ----------------
#define BT_TOT   8192      // B*T
#define SEQ      4096
#define DMODEL   1024
#define DINNER   2048
#define NHEADS   32
#define HEADDIM  64
#define DSTATE   128
#define CONVDIM  2304
#define DINPROJ  4384
#define NCHUNK   32        // per batch
#define CHUNKQ   128

typedef float  f32x4  __attribute__((ext_vector_type(4)));
typedef __bf16 bf16x8 __attribute__((ext_vector_type(8)));

// XOR swizzle of a byte offset within a 256B (or 128B) row
#define SWB(r, b) ((b) ^ (((r) & 7) << 4))

__device__ __forceinline__ u16 f2bf(float f) {
  u32 u = __float_as_uint(f);
  u += 0x7fffu + ((u >> 16) & 1u);
  return (u16)(u >> 16);
}
__device__ __forceinline__ float bf2f(u16 s) {
  return __uint_as_float(((u32)s) << 16);
}

// async global->LDS, 16B per lane; lds dest must be wave-uniform base (+lane*16 implicit)
__device__ __forceinline__ void async_cp16(const void* g, void* l) {
  __builtin_amdgcn_global_load_lds((const __attribute__((address_space(1))) u32*)g,
                                   (__attribute__((address_space(3))) u32*)l, 16, 0, 0);
}

union bfpack { u16 u[8]; bf16x8 v; };

// ---------------- cast f32 -> bf16 (8 elems/thread) ----------------
__global__ __launch_bounds__(256) void cast_bf16(const float* __restrict__ in,
                                                 u16* __restrict__ out, int n8) {
  int i = blockIdx.x * 256 + threadIdx.x;
  if (i >= n8) return;
  const float4* p = (const float4*)in + (size_t)i * 2;
  float4 a = p[0], b = p[1];
  uint4 o;
  o.x = (u32)f2bf(a.x) | ((u32)f2bf(a.y) << 16);
  o.y = (u32)f2bf(a.z) | ((u32)f2bf(a.w) << 16);
  o.z = (u32)f2bf(b.x) | ((u32)f2bf(b.y) << 16);
  o.w = (u32)f2bf(b.z) | ((u32)f2bf(b.w) << 16);
  ((uint4*)out)[i] = o;
}

// ---------------- transpose + cast: in (R,C) f32 -> out (C,R) bf16 ----------------
__global__ __launch_bounds__(256) void tcast(const float* __restrict__ in,
                                             u16* __restrict__ out, int R, int C) {
  __shared__ float tile[32][33];
  int c0 = blockIdx.x * 32, r0 = blockIdx.y * 32;
  int tx = threadIdx.x & 31, ty = threadIdx.x >> 5;  // ty 0..7
  for (int dy = 0; dy < 32; dy += 8)
    tile[ty + dy][tx] = in[(size_t)(r0 + ty + dy) * C + c0 + tx];
  __syncthreads();
  for (int dy = 0; dy < 32; dy += 8)
    out[(size_t)(c0 + ty + dy) * R + r0 + tx] = f2bf(tile[tx][ty + dy]);
}

// ================= GEMM cores (r12 proven: 128x128, BK=64, 2-phase dbuf, 64KB LDS,
//   XCD-chunked + L2-panel ordering). gemm_in is PERSISTENT: 512 blocks, each
//   processes tiles pb, pb+512, ... -> no ragged 5th scheduling round (was 4.375
//   rounds of 512-resident blocks; tail wasted ~13us). 512%8==0 keeps XCD affinity.

// ---- GEMM1: zxbcdt = xb @ Win^T with split epilogue ----
__global__ __launch_bounds__(256) void gemm_in(const u16* __restrict__ A,
                                               const u16* __restrict__ Bt,
                                               const float* __restrict__ dt_bias,
                                               u16* __restrict__ zb,
                                               u16* __restrict__ xbcb,
                                               float* __restrict__ dtb) {
  const int K = DMODEL, Nn = DINPROJ;
  __shared__ u16 sh[32768];
  const int tid = threadIdx.x, lane = tid & 63, wave = tid >> 6;
  const int wm = (wave >> 1) << 6, wn = (wave & 1) << 6;
  const int pb = blockIdx.x;          // 0..511

  for (int tile = pb; tile < 2240; tile += 512) {
    int xcd = tile & 7, c = tile >> 3;          // c in [0,280)
    int dm, n;
    if (c < 256) { int p = c >> 6, r = c & 63; n = p * 8 + (r & 7); dm = r >> 3; }
    else         { int r = c - 256;            n = 32 + r % 3;      dm = r / 3;  }
    const int m0 = (xcd * 8 + dm) * 128;
    const int n0 = n * 128;

    f32x4 acc[4][4] = {};

    auto issue = [&](int buf, int k0) {
#pragma unroll
      for (int s = 0; s < 4; ++s) {
        int idx = s * 256 + tid;
        int row = idx >> 3, k16 = idx & 7;
        int swo = (k16 * 8) ^ ((row & 7) << 3);          // u16 units
        int lofs = (s * 256 + wave * 64) * 8;            // wave-uniform u16 offset
        async_cp16(A + (size_t)(m0 + row) * K + k0 + swo, sh + buf * 16384 + lofs);
        int rn = n0 + row; if (rn > Nn - 1) rn = Nn - 1;
        async_cp16(Bt + (size_t)rn * K + k0 + swo, sh + buf * 16384 + 8192 + lofs);
      }
    };
    issue(0, 0);
    const int nk = K / 64;
    for (int kt = 0; kt < nk; ++kt) {
      int buf = kt & 1;
      asm volatile("s_waitcnt vmcnt(0)" ::: "memory");
      __syncthreads();
      if (kt + 1 < nk) issue(buf ^ 1, (kt + 1) * 64);
      const char* As = (const char*)(sh + buf * 16384);
      const char* Bs = (const char*)(sh + buf * 16384 + 8192);
#pragma unroll
      for (int ks = 0; ks < 2; ++ks) {
        bf16x8 af[4], bfr[4];
#pragma unroll
        for (int t = 0; t < 4; ++t) {
          int r  = wm + t * 16 + (lane & 15);
          int kb = ks * 64 + ((lane >> 4) << 4);
          af[t]  = *(const bf16x8*)(As + r * 128 + SWB(r, kb));
          int rn = wn + t * 16 + (lane & 15);
          bfr[t] = *(const bf16x8*)(Bs + rn * 128 + SWB(rn, kb));
        }
#pragma unroll
        for (int mi = 0; mi < 4; ++mi)
#pragma unroll
          for (int ni = 0; ni < 4; ++ni)
            acc[mi][ni] = __builtin_amdgcn_mfma_f32_16x16x32_bf16(af[mi], bfr[ni], acc[mi][ni], 0, 0, 0);
      }
    }
    __syncthreads();
    if (n0 == 4352) {  // dt block: scalar softplus epilogue (only 32 valid cols)
#pragma unroll
      for (int mi = 0; mi < 4; ++mi) {
#pragma unroll
        for (int ni = 0; ni < 4; ++ni) {
          int r0 = m0 + wm + mi * 16 + ((lane >> 4) << 2);
          int c2 = n0 + wn + ni * 16 + (lane & 15);
          if (c2 < DINPROJ) {
            int h = c2 - 4352;
            float bias = dt_bias[h];
#pragma unroll
            for (int j = 0; j < 4; ++j) {
              float v = acc[mi][ni][j] + bias;
              dtb[(size_t)(r0 + j) * NHEADS + h] = (v > 20.f) ? v : log1pf(__expf(v));
            }
          }
        }
      }
    } else {
      // stage bf16 tile into LDS, then coalesced uint4 writes
#pragma unroll
      for (int mi = 0; mi < 4; ++mi)
#pragma unroll
        for (int ni = 0; ni < 4; ++ni) {
          int il = wm + mi * 16 + ((lane >> 4) << 2);
          int cl = wn + ni * 16 + (lane & 15);
#pragma unroll
          for (int j = 0; j < 4; ++j)
            *(u16*)((char*)sh + (il + j) * 256 + SWB(il + j, 2 * cl)) = f2bf(acc[mi][ni][j]);
        }
      __syncthreads();
      u16* dst; int ldst, n0c;
      if (n0 < 2048) { dst = zb;   ldst = DINNER;  n0c = n0; }
      else           { dst = xbcb; ldst = CONVDIM; n0c = n0 - 2048; }
#pragma unroll
      for (int s = 0; s < 8; ++s) {   // 128 rows x 16 uint4 = 2048 = 8*256
        int idx = s * 256 + tid;
        int r = idx >> 4, n16 = idx & 15;
        uint4 v = *(const uint4*)((char*)sh + r * 256 + SWB(r, n16 * 16));
        *(uint4*)(dst + (size_t)(m0 + r) * ldst + n0c + n16 * 8) = v;
      }
    }
    __syncthreads();   // staging LDS reads done before next tile's issue(0) overwrites
  }
}

// ---- GEMM2: out = yb @ Wout^T, f32 output (512 blocks = exactly 2/CU, no tail) ----
__global__ __launch_bounds__(256) void gemm_out(const u16* __restrict__ A,
                                                const u16* __restrict__ Bt,
                                                float* __restrict__ C) {
  const int K = DINNER, Nn = DMODEL;
  __shared__ u16 sh[32768];
  const int tid = threadIdx.x, lane = tid & 63, wave = tid >> 6;
  const int wm = (wave >> 1) << 6, wn = (wave & 1) << 6;
  // grid (8,64) -> 512 blocks, 64/XCD; panels of 4n x 8m (WS = 2MB+2MB)
  int flat = blockIdx.y * gridDim.x + blockIdx.x;
  int xcd = flat & 7, c = flat >> 3;          // c in [0,64)
  int p = c >> 5, r = c & 31;
  int n = p * 4 + (r & 3), dm = r >> 2;
  const int m0 = (xcd * 8 + dm) * 128;
  const int n0 = n * 128;

  f32x4 acc[4][4] = {};
  auto issue = [&](int buf, int k0) {
#pragma unroll
    for (int s = 0; s < 4; ++s) {
      int idx = s * 256 + tid;
      int row = idx >> 3, k16 = idx & 7;
      int swo = (k16 * 8) ^ ((row & 7) << 3);
      int lofs = (s * 256 + wave * 64) * 8;
      async_cp16(A + (size_t)(m0 + row) * K + k0 + swo, sh + buf * 16384 + lofs);
      async_cp16(Bt + (size_t)(n0 + row) * K + k0 + swo, sh + buf * 16384 + 8192 + lofs);
    }
  };
  issue(0, 0);
  const int nk = K / 64;
  for (int kt = 0; kt < nk; ++kt) {
    int buf = kt & 1;
    asm volatile("s_waitcnt vmcnt(0)" ::: "memory");
    __syncthreads();
    if (kt + 1 < nk) issue(buf ^ 1, (kt + 1) * 64);
    const char* As = (const char*)(sh + buf * 16384);
    const char* Bs = (const char*)(sh + buf * 16384 + 8192);
#pragma unroll
    for (int ks = 0; ks < 2; ++ks) {
      bf16x8 af[4], bfr[4];
#pragma unroll
      for (int t = 0; t < 4; ++t) {
        int r2 = wm + t * 16 + (lane & 15);
        int kb = ks * 64 + ((lane >> 4) << 4);
        af[t]  = *(const bf16x8*)(As + r2 * 128 + SWB(r2, kb));
        int rn = wn + t * 16 + (lane & 15);
        bfr[t] = *(const bf16x8*)(Bs + rn * 128 + SWB(rn, kb));
      }
#pragma unroll
      for (int mi = 0; mi < 4; ++mi)
#pragma unroll
        for (int ni = 0; ni < 4; ++ni)
          acc[mi][ni] = __builtin_amdgcn_mfma_f32_16x16x32_bf16(af[mi], bfr[ni], acc[mi][ni], 0, 0, 0);
    }
  }
#pragma unroll
  for (int mi = 0; mi < 4; ++mi) {
#pragma unroll
    for (int ni = 0; ni < 4; ++ni) {
      int r0 = m0 + wm + mi * 16 + ((lane >> 4) << 2);
      int c2 = n0 + wn + ni * 16 + (lane & 15);
#pragma unroll
      for (int j = 0; j < 4; ++j)
        C[(size_t)(r0 + j) * Nn + c2] = acc[mi][ni][j];
    }
  }
}

// -------- depthwise causal conv1d + bias + silu: 8 ch x 8 timesteps per thread --------
// weights contiguous 128B/thread amortized over 8 outputs; tap rows in regs (11 uint4,
// read amplification 1.375x).
__global__ __launch_bounds__(256) void conv_silu(const u16* __restrict__ xbcb,
                                                 const float* __restrict__ cw,
                                                 const float* __restrict__ cb,
                                                 u16* __restrict__ convb) {
  int i = blockIdx.x * 256 + threadIdx.x;   // (BT_TOT/8) * 288 threads
  int bt8 = i / 288, c8 = i - bt8 * 288;
  int c0 = c8 * 8;
  int bt = bt8 * 8;                          // base output row (8 outputs)
  int t = bt & (SEQ - 1);

  float4 w[8];
  const float4* wp = (const float4*)(cw + (size_t)c0 * 4);
#pragma unroll
  for (int q = 0; q < 8; ++q) w[q] = wp[q];
  float4 b0 = ((const float4*)(cb + c0))[0];
  float4 b1 = ((const float4*)(cb + c0))[1];
  float bias[8] = {b0.x, b0.y, b0.z, b0.w, b1.x, b1.y, b1.z, b1.w};

  uint4 rows[11];
#pragma unroll
  for (int rix = 0; rix < 11; ++rix) {
    if (t - 3 + rix >= 0)
      rows[rix] = *(const uint4*)(xbcb + (size_t)(bt - 3 + rix) * CONVDIM + c0);
    else
      rows[rix] = make_uint4(0, 0, 0, 0);
  }

#pragma unroll
  for (int j = 0; j < 8; ++j) {
    float acc[8];
#pragma unroll
    for (int e = 0; e < 8; ++e) acc[e] = bias[e];
#pragma unroll
    for (int k = 0; k < 4; ++k) {
      const u16* e16 = (const u16*)&rows[j + k];
      float wk;
#pragma unroll
      for (int e = 0; e < 8; ++e) {
        wk = (k == 0) ? w[e].x : (k == 1) ? w[e].y : (k == 2) ? w[e].z : w[e].w;
        acc[e] = fmaf(bf2f(e16[e]), wk, acc[e]);
      }
    }
    uint4 o;
    u16* o16 = (u16*)&o;
#pragma unroll
    for (int e = 0; e < 8; ++e) {
      float s = acc[e] / (1.f + __expf(-acc[e]));
      o16[e] = f2bf(s);
    }
    *(uint4*)(convb + (size_t)(bt + j) * CONVDIM + c0) = o;
  }
}

// ---------------- per-(b,c,h) cumsum of dA over chunk; stores LOG2-domain ----------------
__global__ __launch_bounds__(128) void ssd_cumsum(const float* __restrict__ dtb,
                                                  const float* __restrict__ A_log,
                                                  float* __restrict__ dacs) {
  int bch = blockIdx.x;          // (b*32+c)*32+h
  int h = bch & 31, bc = bch >> 5;
  int q = threadIdx.x;
  float A = -__expf(A_log[h]);
  float v = dtb[((size_t)bc * 128 + q) * 32 + h] * A;
#pragma unroll
  for (int o = 1; o < 64; o <<= 1) {
    float u = __shfl_up(v, o, 64);
    if ((q & 63) >= o) v += u;
  }
  __shared__ float w0;
  if (q == 63) w0 = v;
  __syncthreads();
  if (q >= 64) v += w0;
  dacs[(size_t)bch * 128 + q] = v * LOG2E;
}

// ---------------- fused SSD intra per (b,c,h): G -> M -> Y_diag (+D*xh), S^T ----------------
__global__ __launch_bounds__(256) void ssd_intra2(const u16* __restrict__ convb,
                                                  const float* __restrict__ dacs,
                                                  const float* __restrict__ dtb,
                                                  const float* __restrict__ Dv,
                                                  u16* __restrict__ y,
                                                  u16* __restrict__ S) {
  __shared__ u16 Cc[128 * 128];
  __shared__ u16 Bb[128 * 128];
  __shared__ u16 xhT[64 * 128];
  int bch = (blockIdx.x & 7) * 256 + (blockIdx.x >> 3);  // XCD swizzle (2048 %8==0)
  int h = bch & 31, bc = bch >> 5;
  size_t row0 = (size_t)bc * 128;
  int tid = threadIdx.x, lane = tid & 63, wave = tid >> 6;
  const float* cs = dacs + (size_t)bch * 128;   // log2-domain cumsum

#pragma unroll
  for (int s = 0; s < 8; ++s) {
    int idx = s * 256 + tid;
    int r = idx >> 4, n16 = idx & 15;
    uint4 v = *(const uint4*)(convb + (row0 + r) * CONVDIM + (DINNER + DSTATE) + n16 * 8);
    *(uint4*)((char*)Cc + r * 256 + SWB(r, n16 * 16)) = v;
    uint4 w = *(const uint4*)(convb + (row0 + r) * CONVDIM + DINNER + n16 * 8);
    *(uint4*)((char*)Bb + r * 256 + SWB(r, n16 * 16)) = w;
  }
#pragma unroll
  for (int s = 0; s < 4; ++s) {
    int idx = s * 256 + tid;
    int q = idx >> 3, p0 = (idx & 7) * 8;
    uint4 v = *(const uint4*)(convb + (row0 + q) * CONVDIM + h * 64 + p0);
    const u16* e = (const u16*)&v;
#pragma unroll
    for (int k = 0; k < 8; ++k)
      *(u16*)((char*)xhT + (p0 + k) * 256 + SWB(p0 + k, 2 * q)) = e[k];
  }
  __syncthreads();

  // ---- G = C . B^T ----
  f32x4 g[2][8] = {};
#pragma unroll
  for (int ks = 0; ks < 4; ++ks) {
    int kb = ks * 64 + ((lane >> 4) << 4);
    bf16x8 a[2], b[8];
#pragma unroll
    for (int fi = 0; fi < 2; ++fi) {
      int r = 32 * wave + fi * 16 + (lane & 15);
      a[fi] = *(const bf16x8*)((const char*)Cc + r * 256 + SWB(r, kb));
    }
#pragma unroll
    for (int fj = 0; fj < 8; ++fj) {
      int rj = fj * 16 + (lane & 15);
      b[fj] = *(const bf16x8*)((const char*)Bb + rj * 256 + SWB(rj, kb));
    }
#pragma unroll
    for (int fi = 0; fi < 2; ++fi)
#pragma unroll
      for (int fj = 0; fj < 8; ++fj)
        g[fi][fj] = __builtin_amdgcn_mfma_f32_16x16x32_bf16(a[fi], b[fj], g[fi][fj], 0, 0, 0);
  }

  // ---- build M (bf16) into Cc rows owned by this wave ----
#pragma unroll
  for (int fi = 0; fi < 2; ++fi) {
    int ib = 32 * wave + fi * 16 + ((lane >> 4) << 2);
    float ci[4];
#pragma unroll
    for (int r = 0; r < 4; ++r) ci[r] = cs[ib + r];
#pragma unroll
    for (int fj = 0; fj < 8; ++fj) {
      int j = fj * 16 + (lane & 15);
      float cj = cs[j];
      float dj = dtb[(row0 + j) * NHEADS + h];
#pragma unroll
      for (int r = 0; r < 4; ++r) {
        int i = ib + r;
        float m = (j <= i) ? g[fi][fj][r] * exp2f(ci[r] - cj) * dj : 0.f;
        *(u16*)((char*)Cc + i * 256 + SWB(i, 2 * j)) = f2bf(m);
      }
    }
  }

  // ---- Y_diag = M . xh, triangular k-skip; + D*xh; store y (bf16) ----
  f32x4 yd[2][4] = {};
  for (int ks = 0; ks <= wave; ++ks) {
    int kb = ks * 64 + ((lane >> 4) << 4);
    bf16x8 a[2], b[4];
#pragma unroll
    for (int fi = 0; fi < 2; ++fi) {
      int r = 32 * wave + fi * 16 + (lane & 15);
      a[fi] = *(const bf16x8*)((const char*)Cc + r * 256 + SWB(r, kb));
    }
#pragma unroll
    for (int fp = 0; fp < 4; ++fp) {
      int pr = fp * 16 + (lane & 15);
      b[fp] = *(const bf16x8*)((const char*)xhT + pr * 256 + SWB(pr, kb));
    }
#pragma unroll
    for (int fi = 0; fi < 2; ++fi)
#pragma unroll
      for (int fp = 0; fp < 4; ++fp)
        yd[fi][fp] = __builtin_amdgcn_mfma_f32_16x16x32_bf16(a[fi], b[fp], yd[fi][fp], 0, 0, 0);
  }
  {
    float Dh = Dv[h];
#pragma unroll
    for (int fi = 0; fi < 2; ++fi) {
      int ib = 32 * wave + fi * 16 + ((lane >> 4) << 2);
#pragma unroll
      for (int fp = 0; fp < 4; ++fp) {
        int p = fp * 16 + (lane & 15);
#pragma unroll
        for (int r = 0; r < 4; ++r) {
          int i = ib + r;
          float xv = bf2f(*(const u16*)((const char*)xhT + p * 256 + SWB(p, 2 * i)));
          y[(row0 + i) * DINNER + h * 64 + p] = f2bf(yd[fi][fp][r] + Dh * xv);
        }
      }
    }
  }

  // ---- S[n][p] = sum_q (B[q][n]*w_q) * xh[q][p] ----
  float cl = cs[127];
  f32x4 sa[2][4] = {};
#pragma unroll
  for (int ks = 0; ks < 4; ++ks) {
    int qb = ks * 32 + ((lane >> 4) << 3);
    float wv[8];
#pragma unroll
    for (int e = 0; e < 8; ++e)
      wv[e] = exp2f(cl - cs[qb + e]) * dtb[(row0 + qb + e) * NHEADS + h];
    bf16x8 a[2], b[4];
#pragma unroll
    for (int fn = 0; fn < 2; ++fn) {
      int n = 32 * wave + fn * 16 + (lane & 15);
      bfpack t;
#pragma unroll
      for (int e = 0; e < 8; ++e) {
        int q = qb + e;
        float bv = bf2f(*(const u16*)((const char*)Bb + q * 256 + SWB(q, 2 * n)));
        t.u[e] = f2bf(bv * wv[e]);
      }
      a[fn] = t.v;
    }
    int kb = ks * 64 + ((lane >> 4) << 4);
#pragma unroll
    for (int fp = 0; fp < 4; ++fp) {
      int pr = fp * 16 + (lane & 15);
      b[fp] = *(const bf16x8*)((const char*)xhT + pr * 256 + SWB(pr, kb));
    }
#pragma unroll
    for (int fn = 0; fn < 2; ++fn)
#pragma unroll
      for (int fp = 0; fp < 4; ++fp)
        sa[fn][fp] = __builtin_amdgcn_mfma_f32_16x16x32_bf16(a[fn], b[fp], sa[fn][fp], 0, 0, 0);
  }
  __syncthreads();
#pragma unroll
  for (int fn = 0; fn < 2; ++fn) {
    int nb = 32 * wave + fn * 16 + ((lane >> 4) << 2);
#pragma unroll
    for (int fp = 0; fp < 4; ++fp) {
      int p = fp * 16 + (lane & 15);
#pragma unroll
      for (int r = 0; r < 4; ++r)
        *(u16*)((char*)Cc + p * 256 + SWB(p, 2 * (nb + r))) = f2bf(sa[fn][fp][r]);
    }
  }
  __syncthreads();
#pragma unroll
  for (int s = 0; s < 4; ++s) {
    int idx = s * 256 + tid;
    int p = idx >> 4, n16 = idx & 15;
    uint4 v = *(const uint4*)((char*)Cc + p * 256 + SWB(p, n16 * 16));
    *(uint4*)(S + (size_t)bch * 8192 + p * 128 + n16 * 8) = v;
  }
}

// ---------------- inter-chunk scan (in place; S layout [p][n] flat 8192/bch) -------
__global__ __launch_bounds__(256) void ssd_scan(u16* __restrict__ S,
                                                const float* __restrict__ dacs) {
  int f = blockIdx.x * 256 + threadIdx.x;   // 524288 total
  int e = f & 8191;
  int bh = f >> 13;
  int b = bh >> 5, h = bh & 31;
  float carry = 0.f;
  for (int c = 0; c < NCHUNK; ++c) {
    size_t bch = ((size_t)b * 32 + c) * 32 + h;
    size_t off = bch * 8192 + e;
    float s = bf2f(S[off]);
    S[off] = f2bf(carry);
    float cd = exp2f(dacs[bch * 128 + 127]);
    carry = fmaf(carry, cd, s);
  }
}

// ---------------- Y_off: y += exp2(cs_i) * C(128x128) . prev^T-layout (MFMA) ----------------
__global__ __launch_bounds__(256) void ssd_off2(const u16* __restrict__ convb,
                                                const u16* __restrict__ S,
                                                const float* __restrict__ dacs,
                                                u16* __restrict__ y) {
  __shared__ u16 Cc[128 * 128];
  __shared__ u16 pv[64 * 128];   // prev as [p][n]
  int bch = (blockIdx.x & 7) * 256 + (blockIdx.x >> 3);
  int h = bch & 31, bc = bch >> 5;
  size_t row0 = (size_t)bc * 128;
  int tid = threadIdx.x, lane = tid & 63, wave = tid >> 6;
  const float* cs = dacs + (size_t)bch * 128;

#pragma unroll
  for (int s = 0; s < 8; ++s) {
    int idx = s * 256 + tid;
    int r = idx >> 4, n16 = idx & 15;
    uint4 v = *(const uint4*)(convb + (row0 + r) * CONVDIM + (DINNER + DSTATE) + n16 * 8);
    *(uint4*)((char*)Cc + r * 256 + SWB(r, n16 * 16)) = v;
  }
#pragma unroll
  for (int s = 0; s < 4; ++s) {
    int idx = s * 256 + tid;
    int p = idx >> 4, n16 = idx & 15;
    uint4 v = *(const uint4*)(S + (size_t)bch * 8192 + p * 128 + n16 * 8);
    *(uint4*)((char*)pv + p * 256 + SWB(p, n16 * 16)) = v;
  }
  __syncthreads();

  f32x4 acc[2][4] = {};
#pragma unroll
  for (int ks = 0; ks < 4; ++ks) {
    int kb = ks * 64 + ((lane >> 4) << 4);
    bf16x8 a[2], b[4];
#pragma unroll
    for (int fi = 0; fi < 2; ++fi) {
      int r = 32 * wave + fi * 16 + (lane & 15);
      a[fi] = *(const bf16x8*)((const char*)Cc + r * 256 + SWB(r, kb));
    }
#pragma unroll
    for (int fp = 0; fp < 4; ++fp) {
      int pr = fp * 16 + (lane & 15);
      b[fp] = *(const bf16x8*)((const char*)pv + pr * 256 + SWB(pr, kb));
    }
#pragma unroll
    for (int fi = 0; fi < 2; ++fi)
#pragma unroll
      for (int fp = 0; fp < 4; ++fp)
        acc[fi][fp] = __builtin_amdgcn_mfma_f32_16x16x32_bf16(a[fi], b[fp], acc[fi][fp], 0, 0, 0);
  }
#pragma unroll
  for (int fi = 0; fi < 2; ++fi) {
    int ib = 32 * wave + fi * 16 + ((lane >> 4) << 2);
    float ei[4];
#pragma unroll
    for (int r = 0; r < 4; ++r) ei[r] = exp2f(cs[ib + r]);
#pragma unroll
    for (int fp = 0; fp < 4; ++fp) {
      int p = fp * 16 + (lane & 15);
#pragma unroll
      for (int r = 0; r < 4; ++r) {
        u16* yp = &y[(row0 + ib + r) * DINNER + h * 64 + p];
        float cur = bf2f(*yp);
        *yp = f2bf(fmaf(ei[r], acc[fi][fp][r], cur));
      }
    }
  }
}

// ---------------- gated RMSNorm -> bf16 ----------------
__global__ __launch_bounds__(256) void gated_norm(const u16* __restrict__ y,
                                                  const u16* __restrict__ zb,
                                                  const float* __restrict__ normw,
                                                  u16* __restrict__ yb) {
  size_t bt = blockIdx.x;
  int tid = threadIdx.x;
  const u16* yr = y + bt * DINNER;
  const u16* zr = zb + bt * DINNER;
  float g[8];
  float ss = 0.f;
#pragma unroll
  for (int s = 0; s < 8; ++s) {
    int c = tid + s * 256;
    float z = bf2f(zr[c]);
    float v = bf2f(yr[c]) * (z / (1.f + __expf(-z)));
    g[s] = v;
    ss = fmaf(v, v, ss);
  }
#pragma unroll
  for (int o = 1; o < 64; o <<= 1) ss += __shfl_xor(ss, o, 64);
  __shared__ float red[4];
  if ((tid & 63) == 0) red[tid >> 6] = ss;
  __syncthreads();
  float tot = red[0] + red[1] + red[2] + red[3];
  float r = rsqrtf(tot * (1.f / (float)DINNER) + 1e-5f);
#pragma unroll
  for (int s = 0; s < 8; ++s) {
    int c = tid + s * 256;
    yb[bt * DINNER + c] = f2bf(g[s] * r * normw[c]);
  }
}

// ---------------- workspace layout (~198 MiB) ----------------
constexpr size_t SZ_XB   = (size_t)BT_TOT * DMODEL * 2;
constexpr size_t SZ_WIB  = (size_t)DINPROJ * DMODEL * 2;
constexpr size_t SZ_WOB  = (size_t)DMODEL * DINNER * 2;
constexpr size_t SZ_ZB   = (size_t)BT_TOT * DINNER * 2;
constexpr size_t SZ_XBCB = (size_t)BT_TOT * CONVDIM * 2;   // reused by yb
constexpr size_t SZ_DTB  = (size_t)BT_TOT * NHEADS * 4;
constexpr size_t SZ_DACS = (size_t)2048 * 128 * 4;
constexpr size_t SZ_CONV = (size_t)BT_TOT * CONVDIM * 2;
constexpr size_t SZ_SB   = (size_t)2048 * 128 * 64 * 2;
constexpr size_t SZ_Y    = (size_t)BT_TOT * DINNER * 2;    // bf16

constexpr size_t OFF_XB   = 0;
constexpr size_t OFF_WIB  = OFF_XB + SZ_XB;
constexpr size_t OFF_WOB  = OFF_WIB + SZ_WIB;
constexpr size_t OFF_ZB   = OFF_WOB + SZ_WOB;
constexpr size_t OFF_XBCB = OFF_ZB + SZ_ZB;
constexpr size_t OFF_DTB  = OFF_XBCB + SZ_XBCB;
constexpr size_t OFF_DACS = OFF_DTB + SZ_DTB;
constexpr size_t OFF_CONV = OFF_DACS + SZ_DACS;
constexpr size_t OFF_SB   = OFF_CONV + SZ_CONV;
constexpr size_t OFF_Y    = OFF_SB + SZ_SB;
constexpr size_t WS_NEEDED = OFF_Y + SZ_Y;

extern "C" void kernel_launch(void* const* d_in, const int* in_sizes, int n_in,
                              void* d_out, int out_size, void* d_ws, size_t ws_size,
                              hipStream_t stream) {
  (void)in_sizes; (void)n_in; (void)out_size;
  if (ws_size < WS_NEEDED) return;

  const float* x      = (const float*)d_in[0];
  const float* Win    = (const float*)d_in[1];
  const float* cw     = (const float*)d_in[2];
  const float* cb     = (const float*)d_in[3];
  const float* dtbias = (const float*)d_in[4];
  const float* A_log  = (const float*)d_in[5];
  const float* Dv     = (const float*)d_in[6];
  const float* normw  = (const float*)d_in[7];
  const float* Wout   = (const float*)d_in[8];
  float* out = (float*)d_out;

  char* ws = (char*)d_ws;
  u16*   xb    = (u16*)  (ws + OFF_XB);
  u16*   wib   = (u16*)  (ws + OFF_WIB);
  u16*   wob   = (u16*)  (ws + OFF_WOB);
  u16*   zb    = (u16*)  (ws + OFF_ZB);
  u16*   xbcb  = (u16*)  (ws + OFF_XBCB);
  float* dtb   = (float*)(ws + OFF_DTB);
  float* dacs  = (float*)(ws + OFF_DACS);
  u16*   convb = (u16*)  (ws + OFF_CONV);
  u16*   sb    = (u16*)  (ws + OFF_SB);
  u16*   y     = (u16*)  (ws + OFF_Y);
  u16*   yb    = (u16*)  (ws + OFF_XBCB);  // overlay: xbcb dead after conv_silu

  cast_bf16<<<dim3(4096), dim3(256), 0, stream>>>(x, xb, BT_TOT * DMODEL / 8);
  tcast<<<dim3(DINPROJ / 32, DMODEL / 32), dim3(256), 0, stream>>>(Win, wib, DMODEL, DINPROJ);
  tcast<<<dim3(DMODEL / 32, DINNER / 32), dim3(256), 0, stream>>>(Wout, wob, DINNER, DMODEL);

  gemm_in<<<dim3(512), dim3(256), 0, stream>>>(xb, wib, dtbias, zb, xbcb, dtb);

  conv_silu<<<dim3((BT_TOT / 8) * (CONVDIM / 8) / 256), dim3(256), 0, stream>>>(
      xbcb, cw, cb, convb);
  ssd_cumsum<<<dim3(2048), dim3(128), 0, stream>>>(dtb, A_log, dacs);
  ssd_intra2<<<dim3(2048), dim3(256), 0, stream>>>(convb, dacs, dtb, Dv, y, sb);
  ssd_scan<<<dim3(2048), dim3(256), 0, stream>>>(sb, dacs);
  ssd_off2<<<dim3(2048), dim3(256), 0, stream>>>(convb, sb, dacs, y);
  gated_norm<<<dim3(BT_TOT), dim3(256), 0, stream>>>(y, zb, normw, yb);

  gemm_out<<<dim3(8, 64), dim3(256), 0, stream>>>(yb, wob, out);
}

// Round 16
// 290.733 us; speedup vs baseline: 1.1094x; 1.1036x over previous
//
#include <hip/hip_runtime.h>

typedef unsigned short u16;
typedef unsigned int   u32;

#define LOG2E 1.44269504088896340736f

// ---------------- dims ----------------
#define BT_TOT   8192      // B*T
#define SEQ      4096
#define DMODEL   1024
#define DINNER   2048
#define NHEADS   32
#define HEADDIM  64
#define DSTATE   128
#define CONVDIM  2304
#define DINPROJ  4384
#define NCHUNK   32        // per batch
#define CHUNKQ   128

typedef float  f32x4  __attribute__((ext_vector_type(4)));
typedef __bf16 bf16x8 __attribute__((ext_vector_type(8)));

// XOR swizzle of a byte offset within a 256B (or 128B) row
#define SWB(r, b) ((b) ^ (((r) & 7) << 4))

__device__ __forceinline__ u16 f2bf(float f) {
  u32 u = __float_as_uint(f);
  u += 0x7fffu + ((u >> 16) & 1u);
  return (u16)(u >> 16);
}
__device__ __forceinline__ float bf2f(u16 s) {
  return __uint_as_float(((u32)s) << 16);
}

// async global->LDS, 16B per lane; lds dest must be wave-uniform base (+lane*16 implicit)
__device__ __forceinline__ void async_cp16(const void* g, void* l) {
  __builtin_amdgcn_global_load_lds((const __attribute__((address_space(1))) u32*)g,
                                   (__attribute__((address_space(3))) u32*)l, 16, 0, 0);
}

union bfpack { u16 u[8]; bf16x8 v; };

// ---------------- cast f32 -> bf16 (8 elems/thread) ----------------
__global__ __launch_bounds__(256) void cast_bf16(const float* __restrict__ in,
                                                 u16* __restrict__ out, int n8) {
  int i = blockIdx.x * 256 + threadIdx.x;
  if (i >= n8) return;
  const float4* p = (const float4*)in + (size_t)i * 2;
  float4 a = p[0], b = p[1];
  uint4 o;
  o.x = (u32)f2bf(a.x) | ((u32)f2bf(a.y) << 16);
  o.y = (u32)f2bf(a.z) | ((u32)f2bf(a.w) << 16);
  o.z = (u32)f2bf(b.x) | ((u32)f2bf(b.y) << 16);
  o.w = (u32)f2bf(b.z) | ((u32)f2bf(b.w) << 16);
  ((uint4*)out)[i] = o;
}

// ---------------- transpose + cast: in (R,C) f32 -> out (C,R) bf16 ----------------
__global__ __launch_bounds__(256) void tcast(const float* __restrict__ in,
                                             u16* __restrict__ out, int R, int C) {
  __shared__ float tile[32][33];
  int c0 = blockIdx.x * 32, r0 = blockIdx.y * 32;
  int tx = threadIdx.x & 31, ty = threadIdx.x >> 5;  // ty 0..7
  for (int dy = 0; dy < 32; dy += 8)
    tile[ty + dy][tx] = in[(size_t)(r0 + ty + dy) * C + c0 + tx];
  __syncthreads();
  for (int dy = 0; dy < 32; dy += 8)
    out[(size_t)(c0 + ty + dy) * R + r0 + tx] = f2bf(tile[tx][ty + dy]);
}

// ================= GEMM cores (r12 proven: 128x128, BK=64, 2-phase dbuf, 64KB LDS,
//   XCD-chunked + L2-panel ordering; 2 blocks/CU inter-block overlap). =====

// ---- GEMM1: zxbcdt = xb @ Win^T with split epilogue ----
__global__ __launch_bounds__(256) void gemm_in(const u16* __restrict__ A,
                                               const u16* __restrict__ Bt,
                                               const float* __restrict__ dt_bias,
                                               u16* __restrict__ zb,
                                               u16* __restrict__ xbcb,
                                               float* __restrict__ dtb) {
  const int K = DMODEL, Nn = DINPROJ;
  __shared__ u16 sh[32768];
  const int tid = threadIdx.x, lane = tid & 63, wave = tid >> 6;
  const int wm = (wave >> 1) << 6, wn = (wave & 1) << 6;
  // XCD chunk + panel order: grid (35,64) -> 2240 blocks, 280/XCD (8 m-rows x 35 n).
  // Panels of 8n x 8m (last panel 3n x 8m): WS = 2MB A + 2MB B fits 4MB L2.
  int flat = blockIdx.y * gridDim.x + blockIdx.x;
  int xcd = flat & 7, c = flat >> 3;          // c in [0,280)
  int dm, n;
  if (c < 256) { int p = c >> 6, r = c & 63; n = p * 8 + (r & 7); dm = r >> 3; }
  else         { int r = c - 256;            n = 32 + r % 3;      dm = r / 3;  }
  const int m0 = (xcd * 8 + dm) * 128;
  const int n0 = n * 128;

  f32x4 acc[4][4] = {};

  auto issue = [&](int buf, int k0) {
#pragma unroll
    for (int s = 0; s < 4; ++s) {
      int idx = s * 256 + tid;
      int row = idx >> 3, k16 = idx & 7;
      int swo = (k16 * 8) ^ ((row & 7) << 3);          // u16 units
      int lofs = (s * 256 + wave * 64) * 8;            // wave-uniform u16 offset
      async_cp16(A + (size_t)(m0 + row) * K + k0 + swo, sh + buf * 16384 + lofs);
      int rn = n0 + row; if (rn > Nn - 1) rn = Nn - 1;
      async_cp16(Bt + (size_t)rn * K + k0 + swo, sh + buf * 16384 + 8192 + lofs);
    }
  };
  issue(0, 0);
  const int nk = K / 64;
  for (int kt = 0; kt < nk; ++kt) {
    int buf = kt & 1;
    asm volatile("s_waitcnt vmcnt(0)" ::: "memory");
    __syncthreads();
    if (kt + 1 < nk) issue(buf ^ 1, (kt + 1) * 64);
    const char* As = (const char*)(sh + buf * 16384);
    const char* Bs = (const char*)(sh + buf * 16384 + 8192);
#pragma unroll
    for (int ks = 0; ks < 2; ++ks) {
      bf16x8 af[4], bfr[4];
#pragma unroll
      for (int t = 0; t < 4; ++t) {
        int r  = wm + t * 16 + (lane & 15);
        int kb = ks * 64 + ((lane >> 4) << 4);
        af[t]  = *(const bf16x8*)(As + r * 128 + SWB(r, kb));
        int rn = wn + t * 16 + (lane & 15);
        bfr[t] = *(const bf16x8*)(Bs + rn * 128 + SWB(rn, kb));
      }
#pragma unroll
      for (int mi = 0; mi < 4; ++mi)
#pragma unroll
        for (int ni = 0; ni < 4; ++ni)
          acc[mi][ni] = __builtin_amdgcn_mfma_f32_16x16x32_bf16(af[mi], bfr[ni], acc[mi][ni], 0, 0, 0);
    }
  }
  __syncthreads();
  if (n0 == 4352) {  // dt block: scalar softplus epilogue (only 32 valid cols)
#pragma unroll
    for (int mi = 0; mi < 4; ++mi) {
#pragma unroll
      for (int ni = 0; ni < 4; ++ni) {
        int r0 = m0 + wm + mi * 16 + ((lane >> 4) << 2);
        int c2 = n0 + wn + ni * 16 + (lane & 15);
        if (c2 < DINPROJ) {
          int h = c2 - 4352;
          float bias = dt_bias[h];
#pragma unroll
          for (int j = 0; j < 4; ++j) {
            float v = acc[mi][ni][j] + bias;
            dtb[(size_t)(r0 + j) * NHEADS + h] = (v > 20.f) ? v : log1pf(__expf(v));
          }
        }
      }
    }
  } else {
    // stage bf16 tile into LDS, then coalesced uint4 writes
#pragma unroll
    for (int mi = 0; mi < 4; ++mi)
#pragma unroll
      for (int ni = 0; ni < 4; ++ni) {
        int il = wm + mi * 16 + ((lane >> 4) << 2);
        int cl = wn + ni * 16 + (lane & 15);
#pragma unroll
        for (int j = 0; j < 4; ++j)
          *(u16*)((char*)sh + (il + j) * 256 + SWB(il + j, 2 * cl)) = f2bf(acc[mi][ni][j]);
      }
    __syncthreads();
    u16* dst; int ldst, n0c;
    if (n0 < 2048) { dst = zb;   ldst = DINNER;  n0c = n0; }
    else           { dst = xbcb; ldst = CONVDIM; n0c = n0 - 2048; }
#pragma unroll
    for (int s = 0; s < 8; ++s) {   // 128 rows x 16 uint4 = 2048 = 8*256
      int idx = s * 256 + tid;
      int r = idx >> 4, n16 = idx & 15;
      uint4 v = *(const uint4*)((char*)sh + r * 256 + SWB(r, n16 * 16));
      *(uint4*)(dst + (size_t)(m0 + r) * ldst + n0c + n16 * 8) = v;
    }
  }
}

// ---- GEMM2: out = yb @ Wout^T, f32 output ----
__global__ __launch_bounds__(256) void gemm_out(const u16* __restrict__ A,
                                                const u16* __restrict__ Bt,
                                                float* __restrict__ C) {
  const int K = DINNER, Nn = DMODEL;
  __shared__ u16 sh[32768];
  const int tid = threadIdx.x, lane = tid & 63, wave = tid >> 6;
  const int wm = (wave >> 1) << 6, wn = (wave & 1) << 6;
  // grid (8,64) -> 512 blocks, 64/XCD; panels of 4n x 8m (WS = 2MB+2MB)
  int flat = blockIdx.y * gridDim.x + blockIdx.x;
  int xcd = flat & 7, c = flat >> 3;          // c in [0,64)
  int p = c >> 5, r = c & 31;
  int n = p * 4 + (r & 3), dm = r >> 2;
  const int m0 = (xcd * 8 + dm) * 128;
  const int n0 = n * 128;

  f32x4 acc[4][4] = {};
  auto issue = [&](int buf, int k0) {
#pragma unroll
    for (int s = 0; s < 4; ++s) {
      int idx = s * 256 + tid;
      int row = idx >> 3, k16 = idx & 7;
      int swo = (k16 * 8) ^ ((row & 7) << 3);
      int lofs = (s * 256 + wave * 64) * 8;
      async_cp16(A + (size_t)(m0 + row) * K + k0 + swo, sh + buf * 16384 + lofs);
      async_cp16(Bt + (size_t)(n0 + row) * K + k0 + swo, sh + buf * 16384 + 8192 + lofs);
    }
  };
  issue(0, 0);
  const int nk = K / 64;
  for (int kt = 0; kt < nk; ++kt) {
    int buf = kt & 1;
    asm volatile("s_waitcnt vmcnt(0)" ::: "memory");
    __syncthreads();
    if (kt + 1 < nk) issue(buf ^ 1, (kt + 1) * 64);
    const char* As = (const char*)(sh + buf * 16384);
    const char* Bs = (const char*)(sh + buf * 16384 + 8192);
#pragma unroll
    for (int ks = 0; ks < 2; ++ks) {
      bf16x8 af[4], bfr[4];
#pragma unroll
      for (int t = 0; t < 4; ++t) {
        int r2 = wm + t * 16 + (lane & 15);
        int kb = ks * 64 + ((lane >> 4) << 4);
        af[t]  = *(const bf16x8*)(As + r2 * 128 + SWB(r2, kb));
        int rn = wn + t * 16 + (lane & 15);
        bfr[t] = *(const bf16x8*)(Bs + rn * 128 + SWB(rn, kb));
      }
#pragma unroll
      for (int mi = 0; mi < 4; ++mi)
#pragma unroll
        for (int ni = 0; ni < 4; ++ni)
          acc[mi][ni] = __builtin_amdgcn_mfma_f32_16x16x32_bf16(af[mi], bfr[ni], acc[mi][ni], 0, 0, 0);
    }
  }
#pragma unroll
  for (int mi = 0; mi < 4; ++mi) {
#pragma unroll
    for (int ni = 0; ni < 4; ++ni) {
      int r0 = m0 + wm + mi * 16 + ((lane >> 4) << 2);
      int c2 = n0 + wn + ni * 16 + (lane & 15);
#pragma unroll
      for (int j = 0; j < 4; ++j)
        C[(size_t)(r0 + j) * Nn + c2] = acc[mi][ni][j];
    }
  }
}

// -------- depthwise causal conv1d + bias + silu: 8 ch x 8 timesteps per thread --------
// weights contiguous 128B/thread amortized over 8 outputs; tap rows in regs (11 uint4,
// read amplification 1.375x). [kept from r15: attributed ~-11us vs 4-step]
__global__ __launch_bounds__(256) void conv_silu(const u16* __restrict__ xbcb,
                                                 const float* __restrict__ cw,
                                                 const float* __restrict__ cb,
                                                 u16* __restrict__ convb) {
  int i = blockIdx.x * 256 + threadIdx.x;   // (BT_TOT/8) * 288 threads
  int bt8 = i / 288, c8 = i - bt8 * 288;
  int c0 = c8 * 8;
  int bt = bt8 * 8;                          // base output row (8 outputs)
  int t = bt & (SEQ - 1);

  float4 w[8];
  const float4* wp = (const float4*)(cw + (size_t)c0 * 4);
#pragma unroll
  for (int q = 0; q < 8; ++q) w[q] = wp[q];
  float4 b0 = ((const float4*)(cb + c0))[0];
  float4 b1 = ((const float4*)(cb + c0))[1];
  float bias[8] = {b0.x, b0.y, b0.z, b0.w, b1.x, b1.y, b1.z, b1.w};

  uint4 rows[11];
#pragma unroll
  for (int rix = 0; rix < 11; ++rix) {
    if (t - 3 + rix >= 0)
      rows[rix] = *(const uint4*)(xbcb + (size_t)(bt - 3 + rix) * CONVDIM + c0);
    else
      rows[rix] = make_uint4(0, 0, 0, 0);
  }

#pragma unroll
  for (int j = 0; j < 8; ++j) {
    float acc[8];
#pragma unroll
    for (int e = 0; e < 8; ++e) acc[e] = bias[e];
#pragma unroll
    for (int k = 0; k < 4; ++k) {
      const u16* e16 = (const u16*)&rows[j + k];
      float wk;
#pragma unroll
      for (int e = 0; e < 8; ++e) {
        wk = (k == 0) ? w[e].x : (k == 1) ? w[e].y : (k == 2) ? w[e].z : w[e].w;
        acc[e] = fmaf(bf2f(e16[e]), wk, acc[e]);
      }
    }
    uint4 o;
    u16* o16 = (u16*)&o;
#pragma unroll
    for (int e = 0; e < 8; ++e) {
      float s = acc[e] / (1.f + __expf(-acc[e]));
      o16[e] = f2bf(s);
    }
    *(uint4*)(convb + (size_t)(bt + j) * CONVDIM + c0) = o;
  }
}

// ---------------- per-(b,c,h) cumsum of dA over chunk; stores LOG2-domain ----------------
__global__ __launch_bounds__(128) void ssd_cumsum(const float* __restrict__ dtb,
                                                  const float* __restrict__ A_log,
                                                  float* __restrict__ dacs) {
  int bch = blockIdx.x;          // (b*32+c)*32+h
  int h = bch & 31, bc = bch >> 5;
  int q = threadIdx.x;
  float A = -__expf(A_log[h]);
  float v = dtb[((size_t)bc * 128 + q) * 32 + h] * A;
#pragma unroll
  for (int o = 1; o < 64; o <<= 1) {
    float u = __shfl_up(v, o, 64);
    if ((q & 63) >= o) v += u;
  }
  __shared__ float w0;
  if (q == 63) w0 = v;
  __syncthreads();
  if (q >= 64) v += w0;
  dacs[(size_t)bch * 128 + q] = v * LOG2E;
}

// ---------------- fused SSD intra per (b,c,h): G -> M -> Y_diag (+D*xh), S^T ----------------
__global__ __launch_bounds__(256) void ssd_intra2(const u16* __restrict__ convb,
                                                  const float* __restrict__ dacs,
                                                  const float* __restrict__ dtb,
                                                  const float* __restrict__ Dv,
                                                  u16* __restrict__ y,
                                                  u16* __restrict__ S) {
  __shared__ u16 Cc[128 * 128];
  __shared__ u16 Bb[128 * 128];
  __shared__ u16 xhT[64 * 128];
  int bch = (blockIdx.x & 7) * 256 + (blockIdx.x >> 3);  // XCD swizzle (2048 %8==0)
  int h = bch & 31, bc = bch >> 5;
  size_t row0 = (size_t)bc * 128;
  int tid = threadIdx.x, lane = tid & 63, wave = tid >> 6;
  const float* cs = dacs + (size_t)bch * 128;   // log2-domain cumsum

#pragma unroll
  for (int s = 0; s < 8; ++s) {
    int idx = s * 256 + tid;
    int r = idx >> 4, n16 = idx & 15;
    uint4 v = *(const uint4*)(convb + (row0 + r) * CONVDIM + (DINNER + DSTATE) + n16 * 8);
    *(uint4*)((char*)Cc + r * 256 + SWB(r, n16 * 16)) = v;
    uint4 w = *(const uint4*)(convb + (row0 + r) * CONVDIM + DINNER + n16 * 8);
    *(uint4*)((char*)Bb + r * 256 + SWB(r, n16 * 16)) = w;
  }
#pragma unroll
  for (int s = 0; s < 4; ++s) {
    int idx = s * 256 + tid;
    int q = idx >> 3, p0 = (idx & 7) * 8;
    uint4 v = *(const uint4*)(convb + (row0 + q) * CONVDIM + h * 64 + p0);
    const u16* e = (const u16*)&v;
#pragma unroll
    for (int k = 0; k < 8; ++k)
      *(u16*)((char*)xhT + (p0 + k) * 256 + SWB(p0 + k, 2 * q)) = e[k];
  }
  __syncthreads();

  // ---- G = C . B^T ----
  f32x4 g[2][8] = {};
#pragma unroll
  for (int ks = 0; ks < 4; ++ks) {
    int kb = ks * 64 + ((lane >> 4) << 4);
    bf16x8 a[2], b[8];
#pragma unroll
    for (int fi = 0; fi < 2; ++fi) {
      int r = 32 * wave + fi * 16 + (lane & 15);
      a[fi] = *(const bf16x8*)((const char*)Cc + r * 256 + SWB(r, kb));
    }
#pragma unroll
    for (int fj = 0; fj < 8; ++fj) {
      int rj = fj * 16 + (lane & 15);
      b[fj] = *(const bf16x8*)((const char*)Bb + rj * 256 + SWB(rj, kb));
    }
#pragma unroll
    for (int fi = 0; fi < 2; ++fi)
#pragma unroll
      for (int fj = 0; fj < 8; ++fj)
        g[fi][fj] = __builtin_amdgcn_mfma_f32_16x16x32_bf16(a[fi], b[fj], g[fi][fj], 0, 0, 0);
  }

  // ---- build M (bf16) into Cc rows owned by this wave ----
#pragma unroll
  for (int fi = 0; fi < 2; ++fi) {
    int ib = 32 * wave + fi * 16 + ((lane >> 4) << 2);
    float ci[4];
#pragma unroll
    for (int r = 0; r < 4; ++r) ci[r] = cs[ib + r];
#pragma unroll
    for (int fj = 0; fj < 8; ++fj) {
      int j = fj * 16 + (lane & 15);
      float cj = cs[j];
      float dj = dtb[(row0 + j) * NHEADS + h];
#pragma unroll
      for (int r = 0; r < 4; ++r) {
        int i = ib + r;
        float m = (j <= i) ? g[fi][fj][r] * exp2f(ci[r] - cj) * dj : 0.f;
        *(u16*)((char*)Cc + i * 256 + SWB(i, 2 * j)) = f2bf(m);
      }
    }
  }

  // ---- Y_diag = M . xh, triangular k-skip; + D*xh; store y (bf16) ----
  f32x4 yd[2][4] = {};
  for (int ks = 0; ks <= wave; ++ks) {
    int kb = ks * 64 + ((lane >> 4) << 4);
    bf16x8 a[2], b[4];
#pragma unroll
    for (int fi = 0; fi < 2; ++fi) {
      int r = 32 * wave + fi * 16 + (lane & 15);
      a[fi] = *(const bf16x8*)((const char*)Cc + r * 256 + SWB(r, kb));
    }
#pragma unroll
    for (int fp = 0; fp < 4; ++fp) {
      int pr = fp * 16 + (lane & 15);
      b[fp] = *(const bf16x8*)((const char*)xhT + pr * 256 + SWB(pr, kb));
    }
#pragma unroll
    for (int fi = 0; fi < 2; ++fi)
#pragma unroll
      for (int fp = 0; fp < 4; ++fp)
        yd[fi][fp] = __builtin_amdgcn_mfma_f32_16x16x32_bf16(a[fi], b[fp], yd[fi][fp], 0, 0, 0);
  }
  {
    float Dh = Dv[h];
#pragma unroll
    for (int fi = 0; fi < 2; ++fi) {
      int ib = 32 * wave + fi * 16 + ((lane >> 4) << 2);
#pragma unroll
      for (int fp = 0; fp < 4; ++fp) {
        int p = fp * 16 + (lane & 15);
#pragma unroll
        for (int r = 0; r < 4; ++r) {
          int i = ib + r;
          float xv = bf2f(*(const u16*)((const char*)xhT + p * 256 + SWB(p, 2 * i)));
          y[(row0 + i) * DINNER + h * 64 + p] = f2bf(yd[fi][fp][r] + Dh * xv);
        }
      }
    }
  }

  // ---- S[n][p] = sum_q (B[q][n]*w_q) * xh[q][p] ----
  float cl = cs[127];
  f32x4 sa[2][4] = {};
#pragma unroll
  for (int ks = 0; ks < 4; ++ks) {
    int qb = ks * 32 + ((lane >> 4) << 3);
    float wv[8];
#pragma unroll
    for (int e = 0; e < 8; ++e)
      wv[e] = exp2f(cl - cs[qb + e]) * dtb[(row0 + qb + e) * NHEADS + h];
    bf16x8 a[2], b[4];
#pragma unroll
    for (int fn = 0; fn < 2; ++fn) {
      int n = 32 * wave + fn * 16 + (lane & 15);
      bfpack t;
#pragma unroll
      for (int e = 0; e < 8; ++e) {
        int q = qb + e;
        float bv = bf2f(*(const u16*)((const char*)Bb + q * 256 + SWB(q, 2 * n)));
        t.u[e] = f2bf(bv * wv[e]);
      }
      a[fn] = t.v;
    }
    int kb = ks * 64 + ((lane >> 4) << 4);
#pragma unroll
    for (int fp = 0; fp < 4; ++fp) {
      int pr = fp * 16 + (lane & 15);
      b[fp] = *(const bf16x8*)((const char*)xhT + pr * 256 + SWB(pr, kb));
    }
#pragma unroll
    for (int fn = 0; fn < 2; ++fn)
#pragma unroll
      for (int fp = 0; fp < 4; ++fp)
        sa[fn][fp] = __builtin_amdgcn_mfma_f32_16x16x32_bf16(a[fn], b[fp], sa[fn][fp], 0, 0, 0);
  }
  __syncthreads();
#pragma unroll
  for (int fn = 0; fn < 2; ++fn) {
    int nb = 32 * wave + fn * 16 + ((lane >> 4) << 2);
#pragma unroll
    for (int fp = 0; fp < 4; ++fp) {
      int p = fp * 16 + (lane & 15);
#pragma unroll
      for (int r = 0; r < 4; ++r)
        *(u16*)((char*)Cc + p * 256 + SWB(p, 2 * (nb + r))) = f2bf(sa[fn][fp][r]);
    }
  }
  __syncthreads();
#pragma unroll
  for (int s = 0; s < 4; ++s) {
    int idx = s * 256 + tid;
    int p = idx >> 4, n16 = idx & 15;
    uint4 v = *(const uint4*)((char*)Cc + p * 256 + SWB(p, n16 * 16));
    *(uint4*)(S + (size_t)bch * 8192 + p * 128 + n16 * 8) = v;
  }
}

// ---------------- inter-chunk scan (in place; S layout [p][n] flat 8192/bch) -------
__global__ __launch_bounds__(256) void ssd_scan(u16* __restrict__ S,
                                                const float* __restrict__ dacs) {
  int f = blockIdx.x * 256 + threadIdx.x;   // 524288 total
  int e = f & 8191;
  int bh = f >> 13;
  int b = bh >> 5, h = bh & 31;
  float carry = 0.f;
  for (int c = 0; c < NCHUNK; ++c) {
    size_t bch = ((size_t)b * 32 + c) * 32 + h;
    size_t off = bch * 8192 + e;
    float s = bf2f(S[off]);
    S[off] = f2bf(carry);
    float cd = exp2f(dacs[bch * 128 + 127]);
    carry = fmaf(carry, cd, s);
  }
}

// ---------------- Y_off: y += exp2(cs_i) * C(128x128) . prev^T-layout (MFMA) ----------------
__global__ __launch_bounds__(256) void ssd_off2(const u16* __restrict__ convb,
                                                const u16* __restrict__ S,
                                                const float* __restrict__ dacs,
                                                u16* __restrict__ y) {
  __shared__ u16 Cc[128 * 128];
  __shared__ u16 pv[64 * 128];   // prev as [p][n]
  int bch = (blockIdx.x & 7) * 256 + (blockIdx.x >> 3);
  int h = bch & 31, bc = bch >> 5;
  size_t row0 = (size_t)bc * 128;
  int tid = threadIdx.x, lane = tid & 63, wave = tid >> 6;
  const float* cs = dacs + (size_t)bch * 128;

#pragma unroll
  for (int s = 0; s < 8; ++s) {
    int idx = s * 256 + tid;
    int r = idx >> 4, n16 = idx & 15;
    uint4 v = *(const uint4*)(convb + (row0 + r) * CONVDIM + (DINNER + DSTATE) + n16 * 8);
    *(uint4*)((char*)Cc + r * 256 + SWB(r, n16 * 16)) = v;
  }
#pragma unroll
  for (int s = 0; s < 4; ++s) {
    int idx = s * 256 + tid;
    int p = idx >> 4, n16 = idx & 15;
    uint4 v = *(const uint4*)(S + (size_t)bch * 8192 + p * 128 + n16 * 8);
    *(uint4*)((char*)pv + p * 256 + SWB(p, n16 * 16)) = v;
  }
  __syncthreads();

  f32x4 acc[2][4] = {};
#pragma unroll
  for (int ks = 0; ks < 4; ++ks) {
    int kb = ks * 64 + ((lane >> 4) << 4);
    bf16x8 a[2], b[4];
#pragma unroll
    for (int fi = 0; fi < 2; ++fi) {
      int r = 32 * wave + fi * 16 + (lane & 15);
      a[fi] = *(const bf16x8*)((const char*)Cc + r * 256 + SWB(r, kb));
    }
#pragma unroll
    for (int fp = 0; fp < 4; ++fp) {
      int pr = fp * 16 + (lane & 15);
      b[fp] = *(const bf16x8*)((const char*)pv + pr * 256 + SWB(pr, kb));
    }
#pragma unroll
    for (int fi = 0; fi < 2; ++fi)
#pragma unroll
      for (int fp = 0; fp < 4; ++fp)
        acc[fi][fp] = __builtin_amdgcn_mfma_f32_16x16x32_bf16(a[fi], b[fp], acc[fi][fp], 0, 0, 0);
  }
#pragma unroll
  for (int fi = 0; fi < 2; ++fi) {
    int ib = 32 * wave + fi * 16 + ((lane >> 4) << 2);
    float ei[4];
#pragma unroll
    for (int r = 0; r < 4; ++r) ei[r] = exp2f(cs[ib + r]);
#pragma unroll
    for (int fp = 0; fp < 4; ++fp) {
      int p = fp * 16 + (lane & 15);
#pragma unroll
      for (int r = 0; r < 4; ++r) {
        u16* yp = &y[(row0 + ib + r) * DINNER + h * 64 + p];
        float cur = bf2f(*yp);
        *yp = f2bf(fmaf(ei[r], acc[fi][fp][r], cur));
      }
    }
  }
}

// ---------------- gated RMSNorm -> bf16 ----------------
__global__ __launch_bounds__(256) void gated_norm(const u16* __restrict__ y,
                                                  const u16* __restrict__ zb,
                                                  const float* __restrict__ normw,
                                                  u16* __restrict__ yb) {
  size_t bt = blockIdx.x;
  int tid = threadIdx.x;
  const u16* yr = y + bt * DINNER;
  const u16* zr = zb + bt * DINNER;
  float g[8];
  float ss = 0.f;
#pragma unroll
  for (int s = 0; s < 8; ++s) {
    int c = tid + s * 256;
    float z = bf2f(zr[c]);
    float v = bf2f(yr[c]) * (z / (1.f + __expf(-z)));
    g[s] = v;
    ss = fmaf(v, v, ss);
  }
#pragma unroll
  for (int o = 1; o < 64; o <<= 1) ss += __shfl_xor(ss, o, 64);
  __shared__ float red[4];
  if ((tid & 63) == 0) red[tid >> 6] = ss;
  __syncthreads();
  float tot = red[0] + red[1] + red[2] + red[3];
  float r = rsqrtf(tot * (1.f / (float)DINNER) + 1e-5f);
#pragma unroll
  for (int s = 0; s < 8; ++s) {
    int c = tid + s * 256;
    yb[bt * DINNER + c] = f2bf(g[s] * r * normw[c]);
  }
}

// ---------------- workspace layout (~198 MiB) ----------------
constexpr size_t SZ_XB   = (size_t)BT_TOT * DMODEL * 2;
constexpr size_t SZ_WIB  = (size_t)DINPROJ * DMODEL * 2;
constexpr size_t SZ_WOB  = (size_t)DMODEL * DINNER * 2;
constexpr size_t SZ_ZB   = (size_t)BT_TOT * DINNER * 2;
constexpr size_t SZ_XBCB = (size_t)BT_TOT * CONVDIM * 2;   // reused by yb
constexpr size_t SZ_DTB  = (size_t)BT_TOT * NHEADS * 4;
constexpr size_t SZ_DACS = (size_t)2048 * 128 * 4;
constexpr size_t SZ_CONV = (size_t)BT_TOT * CONVDIM * 2;
constexpr size_t SZ_SB   = (size_t)2048 * 128 * 64 * 2;
constexpr size_t SZ_Y    = (size_t)BT_TOT * DINNER * 2;    // bf16

constexpr size_t OFF_XB   = 0;
constexpr size_t OFF_WIB  = OFF_XB + SZ_XB;
constexpr size_t OFF_WOB  = OFF_WIB + SZ_WIB;
constexpr size_t OFF_ZB   = OFF_WOB + SZ_WOB;
constexpr size_t OFF_XBCB = OFF_ZB + SZ_ZB;
constexpr size_t OFF_DTB  = OFF_XBCB + SZ_XBCB;
constexpr size_t OFF_DACS = OFF_DTB + SZ_DTB;
constexpr size_t OFF_CONV = OFF_DACS + SZ_DACS;
constexpr size_t OFF_SB   = OFF_CONV + SZ_CONV;
constexpr size_t OFF_Y    = OFF_SB + SZ_SB;
constexpr size_t WS_NEEDED = OFF_Y + SZ_Y;

extern "C" void kernel_launch(void* const* d_in, const int* in_sizes, int n_in,
                              void* d_out, int out_size, void* d_ws, size_t ws_size,
                              hipStream_t stream) {
  (void)in_sizes; (void)n_in; (void)out_size;
  if (ws_size < WS_NEEDED) return;

  const float* x      = (const float*)d_in[0];
  const float* Win    = (const float*)d_in[1];
  const float* cw     = (const float*)d_in[2];
  const float* cb     = (const float*)d_in[3];
  const float* dtbias = (const float*)d_in[4];
  const float* A_log  = (const float*)d_in[5];
  const float* Dv     = (const float*)d_in[6];
  const float* normw  = (const float*)d_in[7];
  const float* Wout   = (const float*)d_in[8];
  float* out = (float*)d_out;

  char* ws = (char*)d_ws;
  u16*   xb    = (u16*)  (ws + OFF_XB);
  u16*   wib   = (u16*)  (ws + OFF_WIB);
  u16*   wob   = (u16*)  (ws + OFF_WOB);
  u16*   zb    = (u16*)  (ws + OFF_ZB);
  u16*   xbcb  = (u16*)  (ws + OFF_XBCB);
  float* dtb   = (float*)(ws + OFF_DTB);
  float* dacs  = (float*)(ws + OFF_DACS);
  u16*   convb = (u16*)  (ws + OFF_CONV);
  u16*   sb    = (u16*)  (ws + OFF_SB);
  u16*   y     = (u16*)  (ws + OFF_Y);
  u16*   yb    = (u16*)  (ws + OFF_XBCB);  // overlay: xbcb dead after conv_silu

  cast_bf16<<<dim3(4096), dim3(256), 0, stream>>>(x, xb, BT_TOT * DMODEL / 8);
  tcast<<<dim3(DINPROJ / 32, DMODEL / 32), dim3(256), 0, stream>>>(Win, wib, DMODEL, DINPROJ);
  tcast<<<dim3(DMODEL / 32, DINNER / 32), dim3(256), 0, stream>>>(Wout, wob, DINNER, DMODEL);

  gemm_in<<<dim3(35, 64), dim3(256), 0, stream>>>(xb, wib, dtbias, zb, xbcb, dtb);

  conv_silu<<<dim3((BT_TOT / 8) * (CONVDIM / 8) / 256), dim3(256), 0, stream>>>(
      xbcb, cw, cb, convb);
  ssd_cumsum<<<dim3(2048), dim3(128), 0, stream>>>(dtb, A_log, dacs);
  ssd_intra2<<<dim3(2048), dim3(256), 0, stream>>>(convb, dacs, dtb, Dv, y, sb);
  ssd_scan<<<dim3(2048), dim3(256), 0, stream>>>(sb, dacs);
  ssd_off2<<<dim3(2048), dim3(256), 0, stream>>>(convb, sb, dacs, y);
  gated_norm<<<dim3(BT_TOT), dim3(256), 0, stream>>>(y, zb, normw, yb);

  gemm_out<<<dim3(8, 64), dim3(256), 0, stream>>>(yb, wob, out);
}